// Round 4
// baseline (4348.220 us; speedup 1.0000x reference)
//
#include <hip/hip_runtime.h>

#define N_NODES 50000
#define N_EDGES 1600000
#define BN_EPS 1e-5f

// ---------------- degree / dinv ----------------

__global__ __launch_bounds__(256) void deg_k(const int* __restrict__ ei, float* __restrict__ deg) {
    int e = blockIdx.x * 256 + threadIdx.x;
    if (e < N_EDGES) atomicAdd(&deg[ei[N_EDGES + e]], 1.0f);
}

__global__ __launch_bounds__(256) void dinv_k(const float* __restrict__ deg, float* __restrict__ dinv) {
    int i = blockIdx.x * 256 + threadIdx.x;
    if (i < N_NODES) dinv[i] = rsqrtf(deg[i] + 1.0f);
}

// ---------------- GEMM1: hs1 = (x @ W1) * dinv[row]   [50000,256]x[256,128] ----------------
// BM=64, BN=128, BK=64, 256 threads = 16x16, per-thread 4 rows x 8 cols.

__global__ __launch_bounds__(256) void gemm1_k(const float* __restrict__ X, const float* __restrict__ W,
                                               const float* __restrict__ dinv, float* __restrict__ out) {
    __shared__ float xs[64][64 + 4];
    __shared__ float ws[64][128];
    int tid = threadIdx.x;
    int row0 = blockIdx.x * 64;
    int tx = tid & 15, ty = tid >> 4;
    float acc[4][8] = {};
    for (int k0 = 0; k0 < 256; k0 += 64) {
        // stage x tile: 64 rows x 64 k
#pragma unroll
        for (int i = 0; i < 4; ++i) {
            int f = tid + i * 256;          // float4 id over 1024
            int r = f >> 4;                 // row in tile
            int kk = (f & 15) << 2;         // k in tile
            int grow = row0 + r;
            float4 v = make_float4(0.f, 0.f, 0.f, 0.f);
            if (grow < N_NODES) v = *(const float4*)&X[grow * 256 + k0 + kk];
            xs[kk + 0][r] = v.x; xs[kk + 1][r] = v.y; xs[kk + 2][r] = v.z; xs[kk + 3][r] = v.w;
        }
        // stage W tile: 64 k x 128 n
#pragma unroll
        for (int i = 0; i < 8; ++i) {
            int f = tid + i * 256;          // float4 id over 2048
            int r = f >> 5;                 // k row
            int c = (f & 31) << 2;
            *(float4*)&ws[r][c] = *(const float4*)&W[(k0 + r) * 128 + c];
        }
        __syncthreads();
#pragma unroll 8
        for (int k = 0; k < 64; ++k) {
            float4 xv = *(const float4*)&xs[k][ty * 4];
            float wv[8];
            *(float4*)&wv[0] = *(const float4*)&ws[k][tx * 8];
            *(float4*)&wv[4] = *(const float4*)&ws[k][tx * 8 + 4];
#pragma unroll
            for (int c = 0; c < 8; ++c) {
                acc[0][c] += xv.x * wv[c];
                acc[1][c] += xv.y * wv[c];
                acc[2][c] += xv.z * wv[c];
                acc[3][c] += xv.w * wv[c];
            }
        }
        __syncthreads();
    }
#pragma unroll
    for (int r = 0; r < 4; ++r) {
        int grow = row0 + ty * 4 + r;
        if (grow < N_NODES) {
            float s = dinv[grow];
            float4 o1, o2;
            o1.x = acc[r][0] * s; o1.y = acc[r][1] * s; o1.z = acc[r][2] * s; o1.w = acc[r][3] * s;
            o2.x = acc[r][4] * s; o2.y = acc[r][5] * s; o2.z = acc[r][6] * s; o2.w = acc[r][7] * s;
            *(float4*)&out[grow * 128 + tx * 8] = o1;
            *(float4*)&out[grow * 128 + tx * 8 + 4] = o2;
        }
    }
}

// ---------------- GEMM2: hs2 = (g1 @ W2) * dinv[row]   [50000,128]x[128,64] ----------------
// BM=64, BN=64, BK=64, 256 threads = 16x16, per-thread 4 rows x 4 cols.

__global__ __launch_bounds__(256) void gemm2_k(const float* __restrict__ X, const float* __restrict__ W,
                                               const float* __restrict__ dinv, float* __restrict__ out) {
    __shared__ float xs[64][64 + 4];
    __shared__ float ws[64][64];
    int tid = threadIdx.x;
    int row0 = blockIdx.x * 64;
    int tx = tid & 15, ty = tid >> 4;
    float acc[4][4] = {};
    for (int k0 = 0; k0 < 128; k0 += 64) {
        // stage x tile: 64 rows x 64 k (stride 128)
#pragma unroll
        for (int i = 0; i < 4; ++i) {
            int f = tid + i * 256;
            int r = f >> 4;
            int kk = (f & 15) << 2;
            int grow = row0 + r;
            float4 v = make_float4(0.f, 0.f, 0.f, 0.f);
            if (grow < N_NODES) v = *(const float4*)&X[grow * 128 + k0 + kk];
            xs[kk + 0][r] = v.x; xs[kk + 1][r] = v.y; xs[kk + 2][r] = v.z; xs[kk + 3][r] = v.w;
        }
        // stage W tile: 64 k x 64 n
#pragma unroll
        for (int i = 0; i < 4; ++i) {
            int f = tid + i * 256;          // float4 id over 1024
            int r = f >> 4;
            int c = (f & 15) << 2;
            *(float4*)&ws[r][c] = *(const float4*)&W[(k0 + r) * 64 + c];
        }
        __syncthreads();
#pragma unroll 8
        for (int k = 0; k < 64; ++k) {
            float4 xv = *(const float4*)&xs[k][ty * 4];
            float4 wv = *(const float4*)&ws[k][tx * 4];
#pragma unroll
            for (int c = 0; c < 4; ++c) {
                float w = (c == 0) ? wv.x : (c == 1) ? wv.y : (c == 2) ? wv.z : wv.w;
                acc[0][c] += xv.x * w;
                acc[1][c] += xv.y * w;
                acc[2][c] += xv.z * w;
                acc[3][c] += xv.w * w;
            }
        }
        __syncthreads();
    }
#pragma unroll
    for (int r = 0; r < 4; ++r) {
        int grow = row0 + ty * 4 + r;
        if (grow < N_NODES) {
            float s = dinv[grow];
            float4 o;
            o.x = acc[r][0] * s; o.y = acc[r][1] * s; o.z = acc[r][2] * s; o.w = acc[r][3] * s;
            *(float4*)&out[grow * 64 + tx * 4] = o;
        }
    }
}

// ---------------- edge scatter-add (atomics) ----------------
// layer1: 128 cols, 32 threads/edge (float4 each), 8 edges/block

__global__ __launch_bounds__(256) void edge128_k(const int* __restrict__ ei, const float* __restrict__ hs,
                                                 float* __restrict__ agg) {
    int tid = threadIdx.x;
    int e = blockIdx.x * 8 + (tid >> 5);
    if (e >= N_EDGES) return;
    int c4 = (tid & 31) << 2;
    int s = ei[e];
    int d = ei[N_EDGES + e];
    float4 v = *(const float4*)&hs[s * 128 + c4];
    float* a = &agg[d * 128 + c4];
    atomicAdd(a + 0, v.x);
    atomicAdd(a + 1, v.y);
    atomicAdd(a + 2, v.z);
    atomicAdd(a + 3, v.w);
}

// layer2: 64 cols, 16 threads/edge, 16 edges/block

__global__ __launch_bounds__(256) void edge64_k(const int* __restrict__ ei, const float* __restrict__ hs,
                                                float* __restrict__ agg) {
    int tid = threadIdx.x;
    int e = blockIdx.x * 16 + (tid >> 4);
    if (e >= N_EDGES) return;
    int c4 = (tid & 15) << 2;
    int s = ei[e];
    int d = ei[N_EDGES + e];
    float4 v = *(const float4*)&hs[s * 64 + c4];
    float* a = &agg[d * 64 + c4];
    atomicAdd(a + 0, v.x);
    atomicAdd(a + 1, v.y);
    atomicAdd(a + 2, v.z);
    atomicAdd(a + 3, v.w);
}

// ---------------- post layer1: g1 = bn1(relu(dinv*(agg+hs) + b1)), in-place over agg ----------------

__global__ __launch_bounds__(256) void post1_k(const float* __restrict__ hs, float* __restrict__ agg,
                                               const float* __restrict__ dinv,
                                               const float* __restrict__ bias,
                                               const float* __restrict__ gamma, const float* __restrict__ beta,
                                               const float* __restrict__ mean, const float* __restrict__ var) {
    int idx = blockIdx.x * 256 + threadIdx.x;      // float4 index over N*128/4
    if (idx >= N_NODES * 32) return;
    int i = idx >> 5;
    int c4 = (idx & 31) << 2;
    float di = dinv[i];
    float4 a = *(float4*)&agg[idx * 4];
    float4 h = *(const float4*)&hs[idx * 4];
    float4 bb = *(const float4*)&bias[c4];
    float4 ga = *(const float4*)&gamma[c4];
    float4 be = *(const float4*)&beta[c4];
    float4 mm = *(const float4*)&mean[c4];
    float4 vv = *(const float4*)&var[c4];
    float o[4];
    float av[4] = {a.x, a.y, a.z, a.w};
    float hv[4] = {h.x, h.y, h.z, h.w};
    float bv[4] = {bb.x, bb.y, bb.z, bb.w};
    float gv[4] = {ga.x, ga.y, ga.z, ga.w};
    float ev[4] = {be.x, be.y, be.z, be.w};
    float mv[4] = {mm.x, mm.y, mm.z, mm.w};
    float vv2[4] = {vv.x, vv.y, vv.z, vv.w};
#pragma unroll
    for (int j = 0; j < 4; ++j) {
        float val = di * (av[j] + hv[j]) + bv[j];
        val = fmaxf(val, 0.f);
        o[j] = (val - mv[j]) * rsqrtf(vv2[j] + BN_EPS) * gv[j] + ev[j];
    }
    float4 ov;
    ov.x = o[0]; ov.y = o[1]; ov.z = o[2]; ov.w = o[3];
    *(float4*)&agg[idx * 4] = ov;
}

// ---------------- final: out = bn2(relu(dinv*(agg2+hs2)+b2)) @ Wl + bl ----------------

__global__ __launch_bounds__(256) void final_k(const float* __restrict__ hs2, const float* __restrict__ agg2,
                                               const float* __restrict__ dinv,
                                               const float* __restrict__ b2,
                                               const float* __restrict__ g2, const float* __restrict__ be2,
                                               const float* __restrict__ m2, const float* __restrict__ v2,
                                               const float* __restrict__ Wl, const float* __restrict__ bl,
                                               float* __restrict__ out) {
    __shared__ float sc[64], sh[64], w0[64], w1[64], bb[64];
    int tid = threadIdx.x;
    if (tid < 64) {
        float s = rsqrtf(v2[tid] + BN_EPS) * g2[tid];
        sc[tid] = s;
        sh[tid] = be2[tid] - m2[tid] * s;
        w0[tid] = Wl[tid * 2];
        w1[tid] = Wl[tid * 2 + 1];
        bb[tid] = b2[tid];
    }
    __syncthreads();
    int node = blockIdx.x * 256 + tid;
    if (node >= N_NODES) return;
    float di = dinv[node];
    float a0 = bl[0], a1 = bl[1];
#pragma unroll
    for (int c = 0; c < 64; c += 4) {
        float4 a = *(const float4*)&agg2[node * 64 + c];
        float4 h = *(const float4*)&hs2[node * 64 + c];
        float vv[4] = {a.x + h.x, a.y + h.y, a.z + h.z, a.w + h.w};
#pragma unroll
        for (int j = 0; j < 4; ++j) {
            float val = di * vv[j] + bb[c + j];
            val = fmaxf(val, 0.f);
            float gg = val * sc[c + j] + sh[c + j];
            a0 += gg * w0[c + j];
            a1 += gg * w1[c + j];
        }
    }
    out[node * 2] = a0;
    out[node * 2 + 1] = a1;
}

// ---------------- launch ----------------

extern "C" void kernel_launch(void* const* d_in, const int* in_sizes, int n_in,
                              void* d_out, int out_size, void* d_ws, size_t ws_size,
                              hipStream_t stream) {
    const float* x   = (const float*)d_in[0];
    const int*   ei  = (const int*)d_in[1];
    const float* W1  = (const float*)d_in[2];
    const float* b1  = (const float*)d_in[3];
    const float* W2  = (const float*)d_in[4];
    const float* b2  = (const float*)d_in[5];
    const float* g1p = (const float*)d_in[6];
    const float* be1 = (const float*)d_in[7];
    const float* m1  = (const float*)d_in[8];
    const float* v1  = (const float*)d_in[9];
    const float* g2p = (const float*)d_in[10];
    const float* be2 = (const float*)d_in[11];
    const float* m2  = (const float*)d_in[12];
    const float* v2  = (const float*)d_in[13];
    const float* Wl  = (const float*)d_in[14];
    const float* bl  = (const float*)d_in[15];
    float* out = (float*)d_out;

    float* ws   = (float*)d_ws;
    float* dinv = ws;                       // 50176
    float* deg  = ws + 50176;               // 50176
    float* bufA = ws + 100352;              // 6.4M floats: hs1, later hs2
    float* bufB = bufA + 6400000;           // 6.4M floats: agg1 -> g1 -> agg2

    hipMemsetAsync(deg, 0, N_NODES * sizeof(float), stream);
    hipMemsetAsync(bufB, 0, (size_t)N_NODES * 128 * sizeof(float), stream);

    deg_k<<<(N_EDGES + 255) / 256, 256, 0, stream>>>(ei, deg);
    dinv_k<<<(N_NODES + 255) / 256, 256, 0, stream>>>(deg, dinv);

    gemm1_k<<<(N_NODES + 63) / 64, 256, 0, stream>>>(x, W1, dinv, bufA);
    edge128_k<<<N_EDGES / 8, 256, 0, stream>>>(ei, bufA, bufB);
    post1_k<<<(N_NODES * 32 + 255) / 256, 256, 0, stream>>>(bufA, bufB, dinv, b1, g1p, be1, m1, v1);

    gemm2_k<<<(N_NODES + 63) / 64, 256, 0, stream>>>(bufB, W2, dinv, bufA);
    hipMemsetAsync(bufB, 0, (size_t)N_NODES * 64 * sizeof(float), stream);
    edge64_k<<<N_EDGES / 16, 256, 0, stream>>>(ei, bufA, bufB);

    final_k<<<(N_NODES + 255) / 256, 256, 0, stream>>>(bufA, bufB, dinv, b2, g2p, be2, m2, v2, Wl, bl, out);
}

// Round 5
// 778.883 us; speedup vs baseline: 5.5826x; 5.5826x over previous
//
#include <hip/hip_runtime.h>

#define N_NODES 50000
#define N_EDGES 1600000
#define BN_EPS 1e-5f
#define SCAN_T 1024
#define CHUNK ((N_NODES + SCAN_T - 1) / SCAN_T)   // 49

// ================= CSR build =================

__global__ __launch_bounds__(256) void hist_k(const int* __restrict__ ei, int* __restrict__ cnt) {
    int e = blockIdx.x * 256 + threadIdx.x;
    if (e < N_EDGES) atomicAdd(&cnt[ei[N_EDGES + e]], 1);
}

// single block: exclusive scan of cnt -> cursor; dinv = rsqrt(cnt+1)
__global__ __launch_bounds__(SCAN_T) void scan_k(const int* __restrict__ cnt, int* __restrict__ cursor,
                                                 float* __restrict__ dinv) {
    __shared__ int wsum[16];
    int t = threadIdx.x;
    int base = t * CHUNK;
    int s = 0;
#pragma unroll
    for (int i = 0; i < CHUNK; ++i) {
        int idx = base + i;
        if (idx < N_NODES) s += cnt[idx];
    }
    // inclusive shuffle-scan within wave
    int v = s;
#pragma unroll
    for (int d = 1; d < 64; d <<= 1) {
        int n = __shfl_up(v, d);
        if ((t & 63) >= d) v += n;
    }
    if ((t & 63) == 63) wsum[t >> 6] = v;
    __syncthreads();
    if (t < 16) {
        int w = wsum[t];
#pragma unroll
        for (int d = 1; d < 16; d <<= 1) {
            int n = __shfl_up(w, d);
            if (t >= d) w += n;
        }
        wsum[t] = w;
    }
    __syncthreads();
    int wbase = (t >> 6) ? wsum[(t >> 6) - 1] : 0;
    int run = v + wbase - s;   // exclusive start of this thread's chunk
#pragma unroll
    for (int i = 0; i < CHUNK; ++i) {
        int idx = base + i;
        if (idx < N_NODES) {
            cursor[idx] = run;
            int c = cnt[idx];
            dinv[idx] = rsqrtf((float)c + 1.0f);
            run += c;
        }
    }
}

// scatter src ids into dst-sorted order; cursor becomes INCLUSIVE offsets after this
__global__ __launch_bounds__(256) void reorder_k(const int* __restrict__ ei, int* __restrict__ cursor,
                                                 int* __restrict__ esrc) {
    int e = blockIdx.x * 256 + threadIdx.x;
    if (e >= N_EDGES) return;
    int s = ei[e];
    int d = ei[N_EDGES + e];
    int pos = atomicAdd(&cursor[d], 1);
    esrc[pos] = s;
}

// ================= GEMM1: hs1 = (x @ W1) * dinv[row]  [50000,256]x[256,128] =================

__global__ __launch_bounds__(256) void gemm1_k(const float* __restrict__ X, const float* __restrict__ W,
                                               const float* __restrict__ dinv, float* __restrict__ out) {
    __shared__ float xs[64][64 + 4];
    __shared__ float ws[64][128];
    int tid = threadIdx.x;
    int row0 = blockIdx.x * 64;
    int tx = tid & 15, ty = tid >> 4;
    float acc[4][8] = {};
    for (int k0 = 0; k0 < 256; k0 += 64) {
#pragma unroll
        for (int i = 0; i < 4; ++i) {
            int f = tid + i * 256;
            int r = f >> 4;
            int kk = (f & 15) << 2;
            int grow = row0 + r;
            float4 v = make_float4(0.f, 0.f, 0.f, 0.f);
            if (grow < N_NODES) v = *(const float4*)&X[grow * 256 + k0 + kk];
            xs[kk + 0][r] = v.x; xs[kk + 1][r] = v.y; xs[kk + 2][r] = v.z; xs[kk + 3][r] = v.w;
        }
#pragma unroll
        for (int i = 0; i < 8; ++i) {
            int f = tid + i * 256;
            int r = f >> 5;
            int c = (f & 31) << 2;
            *(float4*)&ws[r][c] = *(const float4*)&W[(k0 + r) * 128 + c];
        }
        __syncthreads();
#pragma unroll 8
        for (int k = 0; k < 64; ++k) {
            float4 xv = *(const float4*)&xs[k][ty * 4];
            float wv[8];
            *(float4*)&wv[0] = *(const float4*)&ws[k][tx * 8];
            *(float4*)&wv[4] = *(const float4*)&ws[k][tx * 8 + 4];
#pragma unroll
            for (int c = 0; c < 8; ++c) {
                acc[0][c] += xv.x * wv[c];
                acc[1][c] += xv.y * wv[c];
                acc[2][c] += xv.z * wv[c];
                acc[3][c] += xv.w * wv[c];
            }
        }
        __syncthreads();
    }
#pragma unroll
    for (int r = 0; r < 4; ++r) {
        int grow = row0 + ty * 4 + r;
        if (grow < N_NODES) {
            float s = dinv[grow];
            float4 o1, o2;
            o1.x = acc[r][0] * s; o1.y = acc[r][1] * s; o1.z = acc[r][2] * s; o1.w = acc[r][3] * s;
            o2.x = acc[r][4] * s; o2.y = acc[r][5] * s; o2.z = acc[r][6] * s; o2.w = acc[r][7] * s;
            *(float4*)&out[grow * 128 + tx * 8] = o1;
            *(float4*)&out[grow * 128 + tx * 8 + 4] = o2;
        }
    }
}

// ================= GEMM2: hs2 = (g1 @ W2) * dinv[row]  [50000,128]x[128,64] =================

__global__ __launch_bounds__(256) void gemm2_k(const float* __restrict__ X, const float* __restrict__ W,
                                               const float* __restrict__ dinv, float* __restrict__ out) {
    __shared__ float xs[64][64 + 4];
    __shared__ float ws[64][64];
    int tid = threadIdx.x;
    int row0 = blockIdx.x * 64;
    int tx = tid & 15, ty = tid >> 4;
    float acc[4][4] = {};
    for (int k0 = 0; k0 < 128; k0 += 64) {
#pragma unroll
        for (int i = 0; i < 4; ++i) {
            int f = tid + i * 256;
            int r = f >> 4;
            int kk = (f & 15) << 2;
            int grow = row0 + r;
            float4 v = make_float4(0.f, 0.f, 0.f, 0.f);
            if (grow < N_NODES) v = *(const float4*)&X[grow * 128 + k0 + kk];
            xs[kk + 0][r] = v.x; xs[kk + 1][r] = v.y; xs[kk + 2][r] = v.z; xs[kk + 3][r] = v.w;
        }
#pragma unroll
        for (int i = 0; i < 4; ++i) {
            int f = tid + i * 256;
            int r = f >> 4;
            int c = (f & 15) << 2;
            *(float4*)&ws[r][c] = *(const float4*)&W[(k0 + r) * 64 + c];
        }
        __syncthreads();
#pragma unroll 8
        for (int k = 0; k < 64; ++k) {
            float4 xv = *(const float4*)&xs[k][ty * 4];
            float4 wv = *(const float4*)&ws[k][tx * 4];
#pragma unroll
            for (int c = 0; c < 4; ++c) {
                float w = (c == 0) ? wv.x : (c == 1) ? wv.y : (c == 2) ? wv.z : wv.w;
                acc[0][c] += xv.x * w;
                acc[1][c] += xv.y * w;
                acc[2][c] += xv.z * w;
                acc[3][c] += xv.w * w;
            }
        }
        __syncthreads();
    }
#pragma unroll
    for (int r = 0; r < 4; ++r) {
        int grow = row0 + ty * 4 + r;
        if (grow < N_NODES) {
            float s = dinv[grow];
            float4 o;
            o.x = acc[r][0] * s; o.y = acc[r][1] * s; o.z = acc[r][2] * s; o.w = acc[r][3] * s;
            *(float4*)&out[grow * 64 + tx * 4] = o;
        }
    }
}

// ================= gather + fused epilogues =================
// layer1: 128 threads per node (2 nodes/block); fused bias+ReLU+BN1 -> g1

__global__ __launch_bounds__(256) void gather128_k(const int* __restrict__ cursor, const int* __restrict__ esrc,
                                                   const float* __restrict__ hs, const float* __restrict__ dinv,
                                                   const float* __restrict__ bias,
                                                   const float* __restrict__ gamma, const float* __restrict__ beta,
                                                   const float* __restrict__ mean, const float* __restrict__ var,
                                                   float* __restrict__ g1out) {
    int tid = threadIdx.x;
    int n = blockIdx.x * 2 + (tid >> 7);
    int col = tid & 127;
    int beg = (n == 0) ? 0 : cursor[n - 1];
    int end = cursor[n];
    float acc = 0.f;
    int e = beg;
    for (; e + 1 < end; e += 2) {
        int s0 = esrc[e], s1 = esrc[e + 1];
        float a = hs[s0 * 128 + col];
        float b = hs[s1 * 128 + col];
        acc += a;
        acc += b;
    }
    if (e < end) acc += hs[esrc[e] * 128 + col];
    float di = dinv[n];
    float val = di * (acc + hs[n * 128 + col]) + bias[col];
    val = fmaxf(val, 0.f);
    float g = (val - mean[col]) * rsqrtf(var[col] + BN_EPS) * gamma[col] + beta[col];
    g1out[n * 128 + col] = g;
}

// layer2: 64 threads (1 wave) per node (4 nodes/block); fused bias+ReLU+BN2+(@Wl+bl) -> out

__global__ __launch_bounds__(256) void gather64_k(const int* __restrict__ cursor, const int* __restrict__ esrc,
                                                  const float* __restrict__ hs, const float* __restrict__ dinv,
                                                  const float* __restrict__ b2,
                                                  const float* __restrict__ g2, const float* __restrict__ be2,
                                                  const float* __restrict__ m2, const float* __restrict__ v2,
                                                  const float* __restrict__ Wl, const float* __restrict__ bl,
                                                  float* __restrict__ out) {
    int tid = threadIdx.x;
    int n = blockIdx.x * 4 + (tid >> 6);
    int lane = tid & 63;
    int beg = (n == 0) ? 0 : cursor[n - 1];
    int end = cursor[n];
    float acc = 0.f;
    int e = beg;
    for (; e + 1 < end; e += 2) {
        int s0 = esrc[e], s1 = esrc[e + 1];
        float a = hs[s0 * 64 + lane];
        float b = hs[s1 * 64 + lane];
        acc += a;
        acc += b;
    }
    if (e < end) acc += hs[esrc[e] * 64 + lane];
    float di = dinv[n];
    float val = di * (acc + hs[n * 64 + lane]) + b2[lane];
    val = fmaxf(val, 0.f);
    float gg = (val - m2[lane]) * rsqrtf(v2[lane] + BN_EPS) * g2[lane] + be2[lane];
    float p0 = gg * Wl[lane * 2];
    float p1 = gg * Wl[lane * 2 + 1];
#pragma unroll
    for (int d = 32; d > 0; d >>= 1) {
        p0 += __shfl_down(p0, d);
        p1 += __shfl_down(p1, d);
    }
    if (lane == 0) {
        out[n * 2] = p0 + bl[0];
        out[n * 2 + 1] = p1 + bl[1];
    }
}

// ================= fallback (atomic) path kernels =================

__global__ __launch_bounds__(256) void deg_k(const int* __restrict__ ei, float* __restrict__ deg) {
    int e = blockIdx.x * 256 + threadIdx.x;
    if (e < N_EDGES) atomicAdd(&deg[ei[N_EDGES + e]], 1.0f);
}

__global__ __launch_bounds__(256) void dinv_k(const float* __restrict__ deg, float* __restrict__ dinv) {
    int i = blockIdx.x * 256 + threadIdx.x;
    if (i < N_NODES) dinv[i] = rsqrtf(deg[i] + 1.0f);
}

__global__ __launch_bounds__(256) void edge128_k(const int* __restrict__ ei, const float* __restrict__ hs,
                                                 float* __restrict__ agg) {
    int tid = threadIdx.x;
    int e = blockIdx.x * 8 + (tid >> 5);
    if (e >= N_EDGES) return;
    int c4 = (tid & 31) << 2;
    int s = ei[e];
    int d = ei[N_EDGES + e];
    float4 v = *(const float4*)&hs[s * 128 + c4];
    float* a = &agg[d * 128 + c4];
    atomicAdd(a + 0, v.x); atomicAdd(a + 1, v.y); atomicAdd(a + 2, v.z); atomicAdd(a + 3, v.w);
}

__global__ __launch_bounds__(256) void edge64_k(const int* __restrict__ ei, const float* __restrict__ hs,
                                                float* __restrict__ agg) {
    int tid = threadIdx.x;
    int e = blockIdx.x * 16 + (tid >> 4);
    if (e >= N_EDGES) return;
    int c4 = (tid & 15) << 2;
    int s = ei[e];
    int d = ei[N_EDGES + e];
    float4 v = *(const float4*)&hs[s * 64 + c4];
    float* a = &agg[d * 64 + c4];
    atomicAdd(a + 0, v.x); atomicAdd(a + 1, v.y); atomicAdd(a + 2, v.z); atomicAdd(a + 3, v.w);
}

__global__ __launch_bounds__(256) void post1_k(const float* __restrict__ hs, float* __restrict__ agg,
                                               const float* __restrict__ dinv,
                                               const float* __restrict__ bias,
                                               const float* __restrict__ gamma, const float* __restrict__ beta,
                                               const float* __restrict__ mean, const float* __restrict__ var) {
    int idx = blockIdx.x * 256 + threadIdx.x;
    if (idx >= N_NODES * 32) return;
    int i = idx >> 5;
    int c4 = (idx & 31) << 2;
    float di = dinv[i];
    float4 a = *(float4*)&agg[idx * 4];
    float4 h = *(const float4*)&hs[idx * 4];
    float o[4];
    float av[4] = {a.x, a.y, a.z, a.w};
    float hv[4] = {h.x, h.y, h.z, h.w};
#pragma unroll
    for (int j = 0; j < 4; ++j) {
        float val = di * (av[j] + hv[j]) + bias[c4 + j];
        val = fmaxf(val, 0.f);
        o[j] = (val - mean[c4 + j]) * rsqrtf(var[c4 + j] + BN_EPS) * gamma[c4 + j] + beta[c4 + j];
    }
    float4 ov; ov.x = o[0]; ov.y = o[1]; ov.z = o[2]; ov.w = o[3];
    *(float4*)&agg[idx * 4] = ov;
}

__global__ __launch_bounds__(256) void final_k(const float* __restrict__ hs2, const float* __restrict__ agg2,
                                               const float* __restrict__ dinv,
                                               const float* __restrict__ b2,
                                               const float* __restrict__ g2, const float* __restrict__ be2,
                                               const float* __restrict__ m2, const float* __restrict__ v2,
                                               const float* __restrict__ Wl, const float* __restrict__ bl,
                                               float* __restrict__ out) {
    __shared__ float sc[64], sh[64], w0[64], w1[64], bb[64];
    int tid = threadIdx.x;
    if (tid < 64) {
        float s = rsqrtf(v2[tid] + BN_EPS) * g2[tid];
        sc[tid] = s;
        sh[tid] = be2[tid] - m2[tid] * s;
        w0[tid] = Wl[tid * 2];
        w1[tid] = Wl[tid * 2 + 1];
        bb[tid] = b2[tid];
    }
    __syncthreads();
    int node = blockIdx.x * 256 + tid;
    if (node >= N_NODES) return;
    float di = dinv[node];
    float a0 = bl[0], a1 = bl[1];
#pragma unroll
    for (int c = 0; c < 64; c += 4) {
        float4 a = *(const float4*)&agg2[node * 64 + c];
        float4 h = *(const float4*)&hs2[node * 64 + c];
        float vv[4] = {a.x + h.x, a.y + h.y, a.z + h.z, a.w + h.w};
#pragma unroll
        for (int j = 0; j < 4; ++j) {
            float val = di * vv[j] + bb[c + j];
            val = fmaxf(val, 0.f);
            float gg = val * sc[c + j] + sh[c + j];
            a0 += gg * w0[c + j];
            a1 += gg * w1[c + j];
        }
    }
    out[node * 2] = a0;
    out[node * 2 + 1] = a1;
}

// ================= launch =================

extern "C" void kernel_launch(void* const* d_in, const int* in_sizes, int n_in,
                              void* d_out, int out_size, void* d_ws, size_t ws_size,
                              hipStream_t stream) {
    const float* x   = (const float*)d_in[0];
    const int*   ei  = (const int*)d_in[1];
    const float* W1  = (const float*)d_in[2];
    const float* b1  = (const float*)d_in[3];
    const float* W2  = (const float*)d_in[4];
    const float* b2  = (const float*)d_in[5];
    const float* g1p = (const float*)d_in[6];
    const float* be1 = (const float*)d_in[7];
    const float* m1  = (const float*)d_in[8];
    const float* v1  = (const float*)d_in[9];
    const float* g2p = (const float*)d_in[10];
    const float* be2 = (const float*)d_in[11];
    const float* m2  = (const float*)d_in[12];
    const float* v2  = (const float*)d_in[13];
    const float* Wl  = (const float*)d_in[14];
    const float* bl  = (const float*)d_in[15];
    float* out = (float*)d_out;

    // fast-path workspace layout (58.4 MB)
    size_t need = ((size_t)N_NODES * 3 + (size_t)N_EDGES + 2 * 6400000 + 64) * sizeof(float);

    if (ws_size >= need) {
        float* ws     = (float*)d_ws;
        float* dinv   = ws;                              // N_NODES floats
        int*   counts = (int*)(ws + N_NODES);            // N_NODES ints
        int*   cursor = counts + N_NODES;                // N_NODES ints
        int*   esrc   = cursor + N_NODES;                // N_EDGES ints
        float* bufA   = (float*)(esrc + N_EDGES);        // 6.4M floats: hs1, later hs2
        float* bufB   = bufA + 6400000;                  // 6.4M floats: g1

        hipMemsetAsync(counts, 0, N_NODES * sizeof(int), stream);
        hist_k<<<(N_EDGES + 255) / 256, 256, 0, stream>>>(ei, counts);
        scan_k<<<1, SCAN_T, 0, stream>>>(counts, cursor, dinv);
        reorder_k<<<(N_EDGES + 255) / 256, 256, 0, stream>>>(ei, cursor, esrc);

        gemm1_k<<<(N_NODES + 63) / 64, 256, 0, stream>>>(x, W1, dinv, bufA);
        gather128_k<<<N_NODES / 2, 256, 0, stream>>>(cursor, esrc, bufA, dinv, b1, g1p, be1, m1, v1, bufB);
        gemm2_k<<<(N_NODES + 63) / 64, 256, 0, stream>>>(bufB, W2, dinv, bufA);
        gather64_k<<<N_NODES / 4, 256, 0, stream>>>(cursor, esrc, bufA, dinv, b2, g2p, be2, m2, v2, Wl, bl, out);
    } else {
        // fallback: proven atomic path
        float* ws   = (float*)d_ws;
        float* dinv = ws;
        float* deg  = ws + 50176;
        float* bufA = ws + 100352;
        float* bufB = bufA + 6400000;

        hipMemsetAsync(deg, 0, N_NODES * sizeof(float), stream);
        hipMemsetAsync(bufB, 0, (size_t)N_NODES * 128 * sizeof(float), stream);

        deg_k<<<(N_EDGES + 255) / 256, 256, 0, stream>>>(ei, deg);
        dinv_k<<<(N_NODES + 255) / 256, 256, 0, stream>>>(deg, dinv);

        gemm1_k<<<(N_NODES + 63) / 64, 256, 0, stream>>>(x, W1, dinv, bufA);
        edge128_k<<<N_EDGES / 8, 256, 0, stream>>>(ei, bufA, bufB);
        post1_k<<<(N_NODES * 32 + 255) / 256, 256, 0, stream>>>(bufA, bufB, dinv, b1, g1p, be1, m1, v1);

        gemm2_k<<<(N_NODES + 63) / 64, 256, 0, stream>>>(bufB, W2, dinv, bufA);
        hipMemsetAsync(bufB, 0, (size_t)N_NODES * 64 * sizeof(float), stream);
        edge64_k<<<N_EDGES / 16, 256, 0, stream>>>(ei, bufA, bufB);

        final_k<<<(N_NODES + 255) / 256, 256, 0, stream>>>(bufA, bufB, dinv, b2, g2p, be2, m2, v2, Wl, bl, out);
    }
}

// Round 6
// 694.423 us; speedup vs baseline: 6.2616x; 1.1216x over previous
//
#include <hip/hip_runtime.h>

#define N_NODES 50000
#define N_EDGES 1600000
#define BN_EPS 1e-5f
#define SCAN_T 1024
#define CHUNK ((N_NODES + SCAN_T - 1) / SCAN_T)   // 49

typedef unsigned int uint32;
typedef unsigned short ushort16;

__device__ __forceinline__ float bf_lo(uint32 u) { return __uint_as_float(u << 16); }
__device__ __forceinline__ float bf_hi(uint32 u) { return __uint_as_float(u & 0xFFFF0000u); }
__device__ __forceinline__ ushort16 f2bf(float f) {
    uint32 u = __float_as_uint(f);
    u = (u + 0x7FFFu + ((u >> 16) & 1u)) >> 16;     // RNE
    return (ushort16)u;
}

// ================= CSR build =================

__global__ __launch_bounds__(256) void hist_k(const int* __restrict__ ei, int* __restrict__ cnt) {
    int e = blockIdx.x * 256 + threadIdx.x;
    if (e < N_EDGES) atomicAdd(&cnt[ei[N_EDGES + e]], 1);
}

// single block: exclusive scan of cnt -> cursor; dinv = rsqrt(cnt+1)
__global__ __launch_bounds__(SCAN_T) void scan_k(const int* __restrict__ cnt, int* __restrict__ cursor,
                                                 float* __restrict__ dinv) {
    __shared__ int wsum[16];
    int t = threadIdx.x;
    int base = t * CHUNK;
    int s = 0;
#pragma unroll
    for (int i = 0; i < CHUNK; ++i) {
        int idx = base + i;
        if (idx < N_NODES) s += cnt[idx];
    }
    int v = s;
#pragma unroll
    for (int d = 1; d < 64; d <<= 1) {
        int n = __shfl_up(v, d);
        if ((t & 63) >= d) v += n;
    }
    if ((t & 63) == 63) wsum[t >> 6] = v;
    __syncthreads();
    if (t < 16) {
        int w = wsum[t];
#pragma unroll
        for (int d = 1; d < 16; d <<= 1) {
            int n = __shfl_up(w, d);
            if (t >= d) w += n;
        }
        wsum[t] = w;
    }
    __syncthreads();
    int wbase = (t >> 6) ? wsum[(t >> 6) - 1] : 0;
    int run = v + wbase - s;
#pragma unroll
    for (int i = 0; i < CHUNK; ++i) {
        int idx = base + i;
        if (idx < N_NODES) {
            cursor[idx] = run;
            int c = cnt[idx];
            dinv[idx] = rsqrtf((float)c + 1.0f);
            run += c;
        }
    }
}

// scatter src ids into dst-sorted order; cursor becomes INCLUSIVE offsets after this
__global__ __launch_bounds__(256) void reorder_k(const int* __restrict__ ei, int* __restrict__ cursor,
                                                 int* __restrict__ esrc) {
    int e = blockIdx.x * 256 + threadIdx.x;
    if (e >= N_EDGES) return;
    int s = ei[e];
    int d = ei[N_EDGES + e];
    int pos = atomicAdd(&cursor[d], 1);
    esrc[pos] = s;
}

// ================= GEMM1: hs1 = bf16( (x @ W1) * dinv[row] )  [50000,256]x[256,128] =================

__global__ __launch_bounds__(256) void gemm1_k(const float* __restrict__ X, const float* __restrict__ W,
                                               const float* __restrict__ dinv, ushort16* __restrict__ outb) {
    __shared__ float xs[64][64 + 4];
    __shared__ float ws[64][128];
    int tid = threadIdx.x;
    int row0 = blockIdx.x * 64;
    int tx = tid & 15, ty = tid >> 4;
    float acc[4][8] = {};
    for (int k0 = 0; k0 < 256; k0 += 64) {
#pragma unroll
        for (int i = 0; i < 4; ++i) {
            int f = tid + i * 256;
            int r = f >> 4;
            int kk = (f & 15) << 2;
            int grow = row0 + r;
            float4 v = make_float4(0.f, 0.f, 0.f, 0.f);
            if (grow < N_NODES) v = *(const float4*)&X[grow * 256 + k0 + kk];
            xs[kk + 0][r] = v.x; xs[kk + 1][r] = v.y; xs[kk + 2][r] = v.z; xs[kk + 3][r] = v.w;
        }
#pragma unroll
        for (int i = 0; i < 8; ++i) {
            int f = tid + i * 256;
            int r = f >> 5;
            int c = (f & 31) << 2;
            *(float4*)&ws[r][c] = *(const float4*)&W[(k0 + r) * 128 + c];
        }
        __syncthreads();
#pragma unroll 8
        for (int k = 0; k < 64; ++k) {
            float4 xv = *(const float4*)&xs[k][ty * 4];
            float wv[8];
            *(float4*)&wv[0] = *(const float4*)&ws[k][tx * 8];
            *(float4*)&wv[4] = *(const float4*)&ws[k][tx * 8 + 4];
#pragma unroll
            for (int c = 0; c < 8; ++c) {
                acc[0][c] += xv.x * wv[c];
                acc[1][c] += xv.y * wv[c];
                acc[2][c] += xv.z * wv[c];
                acc[3][c] += xv.w * wv[c];
            }
        }
        __syncthreads();
    }
#pragma unroll
    for (int r = 0; r < 4; ++r) {
        int grow = row0 + ty * 4 + r;
        if (grow < N_NODES) {
            float s = dinv[grow];
            uint32 w[4];
#pragma unroll
            for (int c = 0; c < 4; ++c) {
                uint32 lo = (uint32)f2bf(acc[r][2 * c] * s);
                uint32 hi = (uint32)f2bf(acc[r][2 * c + 1] * s);
                w[c] = lo | (hi << 16);
            }
            uint4 o; o.x = w[0]; o.y = w[1]; o.z = w[2]; o.w = w[3];
            *(uint4*)&outb[grow * 128 + tx * 8] = o;
        }
    }
}

// ================= GEMM2: hs2 = bf16( (g1 @ W2) * dinv[row] )  [50000,128]x[128,64] =================

__global__ __launch_bounds__(256) void gemm2_k(const float* __restrict__ X, const float* __restrict__ W,
                                               const float* __restrict__ dinv, ushort16* __restrict__ outb) {
    __shared__ float xs[64][64 + 4];
    __shared__ float ws[64][64];
    int tid = threadIdx.x;
    int row0 = blockIdx.x * 64;
    int tx = tid & 15, ty = tid >> 4;
    float acc[4][4] = {};
    for (int k0 = 0; k0 < 128; k0 += 64) {
#pragma unroll
        for (int i = 0; i < 4; ++i) {
            int f = tid + i * 256;
            int r = f >> 4;
            int kk = (f & 15) << 2;
            int grow = row0 + r;
            float4 v = make_float4(0.f, 0.f, 0.f, 0.f);
            if (grow < N_NODES) v = *(const float4*)&X[grow * 128 + k0 + kk];
            xs[kk + 0][r] = v.x; xs[kk + 1][r] = v.y; xs[kk + 2][r] = v.z; xs[kk + 3][r] = v.w;
        }
#pragma unroll
        for (int i = 0; i < 4; ++i) {
            int f = tid + i * 256;
            int r = f >> 4;
            int c = (f & 15) << 2;
            *(float4*)&ws[r][c] = *(const float4*)&W[(k0 + r) * 64 + c];
        }
        __syncthreads();
#pragma unroll 8
        for (int k = 0; k < 64; ++k) {
            float4 xv = *(const float4*)&xs[k][ty * 4];
            float4 wv = *(const float4*)&ws[k][tx * 4];
#pragma unroll
            for (int c = 0; c < 4; ++c) {
                float w = (c == 0) ? wv.x : (c == 1) ? wv.y : (c == 2) ? wv.z : wv.w;
                acc[0][c] += xv.x * w;
                acc[1][c] += xv.y * w;
                acc[2][c] += xv.z * w;
                acc[3][c] += xv.w * w;
            }
        }
        __syncthreads();
    }
#pragma unroll
    for (int r = 0; r < 4; ++r) {
        int grow = row0 + ty * 4 + r;
        if (grow < N_NODES) {
            float s = dinv[grow];
            ushort4 o;
            o.x = f2bf(acc[r][0] * s); o.y = f2bf(acc[r][1] * s);
            o.z = f2bf(acc[r][2] * s); o.w = f2bf(acc[r][3] * s);
            *(ushort4*)&outb[grow * 64 + tx * 4] = o;
        }
    }
}

// ================= gathers (bf16 payload) =================
// layer1: 64 threads/node, thread owns cols {2l, 2l+1} via one 4B load; 4 nodes/block.

__global__ __launch_bounds__(256) void gather128_k(const int* __restrict__ cursor, const int* __restrict__ esrc,
                                                   const ushort16* __restrict__ hsb, const float* __restrict__ dinv,
                                                   const float* __restrict__ bias,
                                                   const float* __restrict__ gamma, const float* __restrict__ beta,
                                                   const float* __restrict__ mean, const float* __restrict__ var,
                                                   float* __restrict__ g1out) {
    int tid = threadIdx.x;
    int n = blockIdx.x * 4 + (tid >> 6);
    int lane = tid & 63;
    int c0 = lane * 2;
    int beg = (n == 0) ? 0 : cursor[n - 1];
    int end = cursor[n];
    float acc0 = 0.f, acc1 = 0.f;
    int e = beg;
    for (; e + 1 < end; e += 2) {
        int s0 = esrc[e], s1 = esrc[e + 1];
        uint32 u0 = *(const uint32*)&hsb[s0 * 128 + c0];
        uint32 u1 = *(const uint32*)&hsb[s1 * 128 + c0];
        acc0 += bf_lo(u0); acc1 += bf_hi(u0);
        acc0 += bf_lo(u1); acc1 += bf_hi(u1);
    }
    if (e < end) {
        uint32 u = *(const uint32*)&hsb[esrc[e] * 128 + c0];
        acc0 += bf_lo(u); acc1 += bf_hi(u);
    }
    uint32 us = *(const uint32*)&hsb[n * 128 + c0];
    float di = dinv[n];
    float v0 = di * (acc0 + bf_lo(us)) + bias[c0];
    float v1 = di * (acc1 + bf_hi(us)) + bias[c0 + 1];
    v0 = fmaxf(v0, 0.f);
    v1 = fmaxf(v1, 0.f);
    float g0 = (v0 - mean[c0]) * rsqrtf(var[c0] + BN_EPS) * gamma[c0] + beta[c0];
    float g1 = (v1 - mean[c0 + 1]) * rsqrtf(var[c0 + 1] + BN_EPS) * gamma[c0 + 1] + beta[c0 + 1];
    float2 o; o.x = g0; o.y = g1;
    *(float2*)&g1out[n * 128 + c0] = o;
}

// layer2: 64 threads/node, 1 col each (2B load); fused bias+ReLU+BN2+(@Wl+bl); 4 nodes/block.

__global__ __launch_bounds__(256) void gather64_k(const int* __restrict__ cursor, const int* __restrict__ esrc,
                                                  const ushort16* __restrict__ hsb, const float* __restrict__ dinv,
                                                  const float* __restrict__ b2,
                                                  const float* __restrict__ g2, const float* __restrict__ be2,
                                                  const float* __restrict__ m2, const float* __restrict__ v2,
                                                  const float* __restrict__ Wl, const float* __restrict__ bl,
                                                  float* __restrict__ out) {
    int tid = threadIdx.x;
    int n = blockIdx.x * 4 + (tid >> 6);
    int lane = tid & 63;
    int beg = (n == 0) ? 0 : cursor[n - 1];
    int end = cursor[n];
    float acc = 0.f;
    int e = beg;
    for (; e + 1 < end; e += 2) {
        int s0 = esrc[e], s1 = esrc[e + 1];
        float a = __uint_as_float(((uint32)hsb[s0 * 64 + lane]) << 16);
        float b = __uint_as_float(((uint32)hsb[s1 * 64 + lane]) << 16);
        acc += a; acc += b;
    }
    if (e < end) acc += __uint_as_float(((uint32)hsb[esrc[e] * 64 + lane]) << 16);
    float self = __uint_as_float(((uint32)hsb[n * 64 + lane]) << 16);
    float di = dinv[n];
    float val = di * (acc + self) + b2[lane];
    val = fmaxf(val, 0.f);
    float gg = (val - m2[lane]) * rsqrtf(v2[lane] + BN_EPS) * g2[lane] + be2[lane];
    float p0 = gg * Wl[lane * 2];
    float p1 = gg * Wl[lane * 2 + 1];
#pragma unroll
    for (int d = 32; d > 0; d >>= 1) {
        p0 += __shfl_down(p0, d);
        p1 += __shfl_down(p1, d);
    }
    if (lane == 0) {
        out[n * 2] = p0 + bl[0];
        out[n * 2 + 1] = p1 + bl[1];
    }
}

// ================= launch =================

extern "C" void kernel_launch(void* const* d_in, const int* in_sizes, int n_in,
                              void* d_out, int out_size, void* d_ws, size_t ws_size,
                              hipStream_t stream) {
    const float* x   = (const float*)d_in[0];
    const int*   ei  = (const int*)d_in[1];
    const float* W1  = (const float*)d_in[2];
    const float* b1  = (const float*)d_in[3];
    const float* W2  = (const float*)d_in[4];
    const float* b2  = (const float*)d_in[5];
    const float* g1p = (const float*)d_in[6];
    const float* be1 = (const float*)d_in[7];
    const float* m1  = (const float*)d_in[8];
    const float* v1  = (const float*)d_in[9];
    const float* g2p = (const float*)d_in[10];
    const float* be2 = (const float*)d_in[11];
    const float* m2  = (const float*)d_in[12];
    const float* v2  = (const float*)d_in[13];
    const float* Wl  = (const float*)d_in[14];
    const float* bl  = (const float*)d_in[15];
    float* out = (float*)d_out;

    // workspace (floats): dinv | counts | cursor | esrc | hs1b(bf16) | g1(f32) | hs2b(bf16)
    float*    ws     = (float*)d_ws;
    float*    dinv   = ws;                               // 50000 f
    int*      counts = (int*)(ws + 50000);               // 50000 i
    int*      cursor = counts + 50000;                   // 50000 i
    int*      esrc   = cursor + 50000;                   // 1.6M i
    ushort16* hs1b   = (ushort16*)(esrc + N_EDGES);      // 6.4M bf16 (3.2M f slots)
    float*    g1buf  = (float*)(hs1b) + 3200000;         // 6.4M f
    ushort16* hs2b   = (ushort16*)(g1buf + 6400000);     // 3.2M bf16 (1.6M f slots)

    hipMemsetAsync(counts, 0, N_NODES * sizeof(int), stream);
    hist_k<<<(N_EDGES + 255) / 256, 256, 0, stream>>>(ei, counts);
    scan_k<<<1, SCAN_T, 0, stream>>>(counts, cursor, dinv);
    reorder_k<<<(N_EDGES + 255) / 256, 256, 0, stream>>>(ei, cursor, esrc);

    gemm1_k<<<(N_NODES + 63) / 64, 256, 0, stream>>>(x, W1, dinv, hs1b);
    gather128_k<<<(N_NODES + 3) / 4, 256, 0, stream>>>(cursor, esrc, hs1b, dinv, b1, g1p, be1, m1, v1, g1buf);
    gemm2_k<<<(N_NODES + 63) / 64, 256, 0, stream>>>(g1buf, W2, dinv, hs2b);
    gather64_k<<<(N_NODES + 3) / 4, 256, 0, stream>>>(cursor, esrc, hs2b, dinv, b2, g2p, be2, m2, v2, Wl, bl, out);
}

// Round 8
// 421.343 us; speedup vs baseline: 10.3199x; 1.6481x over previous
//
#include <hip/hip_runtime.h>

#define N_NODES 50000
#define N_EDGES 1600000
#define BN_EPS 1e-5f

#define BSH 7
#define BKN 128                                   // nodes per bucket
#define NB  ((N_NODES + BKN - 1) / BKN)           // 391 buckets
#define EPT 16
#define EPB (256 * EPT)                           // 4096 edges per block
#define NEB ((N_EDGES + EPB - 1) / EPB)           // 391 blocks

typedef unsigned int uint32;
typedef unsigned short ushort16;

__device__ __forceinline__ float bf_lo(uint32 u) { return __uint_as_float(u << 16); }
__device__ __forceinline__ float bf_hi(uint32 u) { return __uint_as_float(u & 0xFFFF0000u); }
__device__ __forceinline__ ushort16 f2bf(float f) {
    uint32 u = __float_as_uint(f);
    u = (u + 0x7FFFu + ((u >> 16) & 1u)) >> 16;     // RNE
    return (ushort16)u;
}

// ================= CSR build (bucketed, low write-amplification) =================

// Pass A: per-bucket edge counts (LDS histogram -> global atomics)
__global__ __launch_bounds__(256) void bcount_k(const int* __restrict__ ei, int* __restrict__ gcnt) {
    __shared__ int h[NB];
    int t = threadIdx.x;
    for (int i = t; i < NB; i += 256) h[i] = 0;
    __syncthreads();
    int eb = blockIdx.x * EPB;
#pragma unroll
    for (int i = 0; i < EPT; ++i) {
        int e = eb + i * 256 + t;
        if (e < N_EDGES) atomicAdd(&h[ei[N_EDGES + e] >> BSH], 1);
    }
    __syncthreads();
    for (int i = t; i < NB; i += 256) if (h[i]) atomicAdd(&gcnt[i], h[i]);
}

// Pass A2: exclusive scan of 391 bucket counts -> gbase[0..NB], gcursor init
__global__ __launch_bounds__(512) void bscan_k(const int* __restrict__ gcnt, int* __restrict__ gbase,
                                               int* __restrict__ gcursor) {
    __shared__ int wsum[8];
    int t = threadIdx.x;
    int v = (t < NB) ? gcnt[t] : 0;
    int s = v;
#pragma unroll
    for (int d = 1; d < 64; d <<= 1) {
        int n = __shfl_up(s, d);
        if ((t & 63) >= d) s += n;
    }
    if ((t & 63) == 63) wsum[t >> 6] = s;
    __syncthreads();
    if (t < 8) {
        int w = wsum[t];
#pragma unroll
        for (int d = 1; d < 8; d <<= 1) {
            int n = __shfl_up(w, d);
            if (t >= d) w += n;
        }
        wsum[t] = w;
    }
    __syncthreads();
    int wb = (t >> 6) ? wsum[(t >> 6) - 1] : 0;
    int excl = wb + s - v;
    if (t < NB) { gbase[t] = excl; gcursor[t] = excl; }
    if (t == NB - 1) gbase[NB] = excl + v;
}

// Pass B: bin edges bucket-major with per-block chunk reservation (coalesced-ish writes)
__global__ __launch_bounds__(256) void bin_k(const int* __restrict__ ei, int* __restrict__ gcursor,
                                             uint32* __restrict__ ebin) {
    __shared__ int hcnt[NB];
    __shared__ int hbase[NB];
    int t = threadIdx.x;
    for (int i = t; i < NB; i += 256) hcnt[i] = 0;
    __syncthreads();
    int sv[EPT], dv[EPT];
    int eb = blockIdx.x * EPB;
#pragma unroll
    for (int i = 0; i < EPT; ++i) {
        int e = eb + i * 256 + t;
        if (e < N_EDGES) {
            sv[i] = ei[e];
            dv[i] = ei[N_EDGES + e];
            atomicAdd(&hcnt[dv[i] >> BSH], 1);
        } else {
            dv[i] = -1;
        }
    }
    __syncthreads();
    for (int i = t; i < NB; i += 256) {
        int c = hcnt[i];
        hbase[i] = c ? atomicAdd(&gcursor[i], c) : 0;
    }
    __syncthreads();
    for (int i = t; i < NB; i += 256) hcnt[i] = 0;
    __syncthreads();
#pragma unroll
    for (int i = 0; i < EPT; ++i) {
        if (dv[i] >= 0) {
            int b = dv[i] >> BSH;
            int off = atomicAdd(&hcnt[b], 1);
            ebin[hbase[b] + off] = (uint32)sv[i] | ((uint32)(dv[i] & (BKN - 1)) << 16);
        }
    }
}

// Pass C: per-bucket local sort; writes cursor (inclusive), dinv, esrc (ushort)
__global__ __launch_bounds__(256) void bsort_k(const int* __restrict__ gbase, const uint32* __restrict__ ebin,
                                               unsigned short* __restrict__ esrc, int* __restrict__ cursor,
                                               float* __restrict__ dinv) {
    __shared__ int hcnt[BKN];
    __shared__ int hoff[BKN];
    __shared__ int wsum2[2];
    int b = blockIdx.x;
    int t = threadIdx.x;
    int ebeg = gbase[b], eend = gbase[b + 1];
    int n0 = b << BSH;
    int nn = min(BKN, N_NODES - n0);
    if (t < BKN) hcnt[t] = 0;
    __syncthreads();
    for (int e = ebeg + t; e < eend; e += 256) atomicAdd(&hcnt[ebin[e] >> 16], 1);
    __syncthreads();
    int v = (t < BKN) ? hcnt[t] : 0;
    int s = v;
#pragma unroll
    for (int d = 1; d < 64; d <<= 1) {
        int x = __shfl_up(s, d);
        if ((t & 63) >= d) s += x;
    }
    if (t < BKN && (t & 63) == 63) wsum2[t >> 6] = s;
    __syncthreads();
    int wb = ((t >> 6) == 1) ? wsum2[0] : 0;
    int incl = wb + s;                      // inclusive local scan (valid t<128)
    if (t < nn) {
        cursor[n0 + t] = ebeg + incl;
        dinv[n0 + t] = rsqrtf((float)v + 1.0f);
        hoff[t] = ebeg + incl - v;          // exclusive start
    }
    __syncthreads();
    for (int e = ebeg + t; e < eend; e += 256) {
        uint32 p = ebin[e];
        int ld = p >> 16;
        int pos = atomicAdd(&hoff[ld], 1);
        esrc[pos] = (unsigned short)(p & 0xFFFFu);
    }
}

// ================= GEMM1: hs1 = bf16( (x @ W1) * dinv[row] )  [50000,256]x[256,128] =================

__global__ __launch_bounds__(256) void gemm1_k(const float* __restrict__ X, const float* __restrict__ W,
                                               const float* __restrict__ dinv, ushort16* __restrict__ outb) {
    __shared__ float xs[64][64 + 4];
    __shared__ float ws[64][128];
    int tid = threadIdx.x;
    int row0 = blockIdx.x * 64;
    int tx = tid & 15, ty = tid >> 4;
    float acc[4][8] = {};
    for (int k0 = 0; k0 < 256; k0 += 64) {
#pragma unroll
        for (int i = 0; i < 4; ++i) {
            int f = tid + i * 256;
            int r = f >> 4;
            int kk = (f & 15) << 2;
            int grow = row0 + r;
            float4 v = make_float4(0.f, 0.f, 0.f, 0.f);
            if (grow < N_NODES) v = *(const float4*)&X[grow * 256 + k0 + kk];
            xs[kk + 0][r] = v.x; xs[kk + 1][r] = v.y; xs[kk + 2][r] = v.z; xs[kk + 3][r] = v.w;
        }
#pragma unroll
        for (int i = 0; i < 8; ++i) {
            int f = tid + i * 256;
            int r = f >> 5;
            int c = (f & 31) << 2;
            *(float4*)&ws[r][c] = *(const float4*)&W[(k0 + r) * 128 + c];
        }
        __syncthreads();
#pragma unroll 8
        for (int k = 0; k < 64; ++k) {
            float4 xv = *(const float4*)&xs[k][ty * 4];
            float wv[8];
            *(float4*)&wv[0] = *(const float4*)&ws[k][tx * 8];
            *(float4*)&wv[4] = *(const float4*)&ws[k][tx * 8 + 4];
#pragma unroll
            for (int c = 0; c < 8; ++c) {
                acc[0][c] += xv.x * wv[c];
                acc[1][c] += xv.y * wv[c];
                acc[2][c] += xv.z * wv[c];
                acc[3][c] += xv.w * wv[c];
            }
        }
        __syncthreads();
    }
#pragma unroll
    for (int r = 0; r < 4; ++r) {
        int grow = row0 + ty * 4 + r;
        if (grow < N_NODES) {
            float s = dinv[grow];
            uint32 w[4];
#pragma unroll
            for (int c = 0; c < 4; ++c) {
                uint32 lo = (uint32)f2bf(acc[r][2 * c] * s);
                uint32 hi = (uint32)f2bf(acc[r][2 * c + 1] * s);
                w[c] = lo | (hi << 16);
            }
            uint4 o; o.x = w[0]; o.y = w[1]; o.z = w[2]; o.w = w[3];
            *(uint4*)&outb[grow * 128 + tx * 8] = o;
        }
    }
}

// ================= GEMM2: hs2 = bf16( (g1 @ W2) * dinv[row] )  [50000,128]x[128,64] =================

__global__ __launch_bounds__(256) void gemm2_k(const float* __restrict__ X, const float* __restrict__ W,
                                               const float* __restrict__ dinv, ushort16* __restrict__ outb) {
    __shared__ float xs[64][64 + 4];
    __shared__ float ws[64][64];
    int tid = threadIdx.x;
    int row0 = blockIdx.x * 64;
    int tx = tid & 15, ty = tid >> 4;
    float acc[4][4] = {};
    for (int k0 = 0; k0 < 128; k0 += 64) {
#pragma unroll
        for (int i = 0; i < 4; ++i) {
            int f = tid + i * 256;
            int r = f >> 4;
            int kk = (f & 15) << 2;
            int grow = row0 + r;
            float4 v = make_float4(0.f, 0.f, 0.f, 0.f);
            if (grow < N_NODES) v = *(const float4*)&X[grow * 128 + k0 + kk];
            xs[kk + 0][r] = v.x; xs[kk + 1][r] = v.y; xs[kk + 2][r] = v.z; xs[kk + 3][r] = v.w;
        }
#pragma unroll
        for (int i = 0; i < 4; ++i) {
            int f = tid + i * 256;
            int r = f >> 4;
            int c = (f & 15) << 2;
            *(float4*)&ws[r][c] = *(const float4*)&W[(k0 + r) * 64 + c];
        }
        __syncthreads();
#pragma unroll 8
        for (int k = 0; k < 64; ++k) {
            float4 xv = *(const float4*)&xs[k][ty * 4];
            float4 wv = *(const float4*)&ws[k][tx * 4];
#pragma unroll
            for (int c = 0; c < 4; ++c) {
                float w = (c == 0) ? wv.x : (c == 1) ? wv.y : (c == 2) ? wv.z : wv.w;
                acc[0][c] += xv.x * w;
                acc[1][c] += xv.y * w;
                acc[2][c] += xv.z * w;
                acc[3][c] += xv.w * w;
            }
        }
        __syncthreads();
    }
#pragma unroll
    for (int r = 0; r < 4; ++r) {
        int grow = row0 + ty * 4 + r;
        if (grow < N_NODES) {
            float s = dinv[grow];
            ushort4 o;
            o.x = f2bf(acc[r][0] * s); o.y = f2bf(acc[r][1] * s);
            o.z = f2bf(acc[r][2] * s); o.w = f2bf(acc[r][3] * s);
            *(ushort4*)&outb[grow * 64 + tx * 4] = o;
        }
    }
}

// ================= gathers (bf16 payload, ushort esrc) =================
// layer1: 64 threads/node, thread owns cols {2l, 2l+1} via one 4B load; 4 nodes/block.

__global__ __launch_bounds__(256) void gather128_k(const int* __restrict__ cursor, const unsigned short* __restrict__ esrc,
                                                   const ushort16* __restrict__ hsb, const float* __restrict__ dinv,
                                                   const float* __restrict__ bias,
                                                   const float* __restrict__ gamma, const float* __restrict__ beta,
                                                   const float* __restrict__ mean, const float* __restrict__ var,
                                                   float* __restrict__ g1out) {
    int tid = threadIdx.x;
    int n = blockIdx.x * 4 + (tid >> 6);
    int lane = tid & 63;
    int c0 = lane * 2;
    int beg = (n == 0) ? 0 : cursor[n - 1];
    int end = cursor[n];
    float acc0 = 0.f, acc1 = 0.f;
    int e = beg;
    for (; e + 1 < end; e += 2) {
        int s0 = esrc[e], s1 = esrc[e + 1];
        uint32 u0 = *(const uint32*)&hsb[s0 * 128 + c0];
        uint32 u1 = *(const uint32*)&hsb[s1 * 128 + c0];
        acc0 += bf_lo(u0); acc1 += bf_hi(u0);
        acc0 += bf_lo(u1); acc1 += bf_hi(u1);
    }
    if (e < end) {
        uint32 u = *(const uint32*)&hsb[(int)esrc[e] * 128 + c0];
        acc0 += bf_lo(u); acc1 += bf_hi(u);
    }
    uint32 us = *(const uint32*)&hsb[n * 128 + c0];
    float di = dinv[n];
    float v0 = di * (acc0 + bf_lo(us)) + bias[c0];
    float v1 = di * (acc1 + bf_hi(us)) + bias[c0 + 1];
    v0 = fmaxf(v0, 0.f);
    v1 = fmaxf(v1, 0.f);
    float g0 = (v0 - mean[c0]) * rsqrtf(var[c0] + BN_EPS) * gamma[c0] + beta[c0];
    float g1 = (v1 - mean[c0 + 1]) * rsqrtf(var[c0 + 1] + BN_EPS) * gamma[c0 + 1] + beta[c0 + 1];
    float2 o; o.x = g0; o.y = g1;
    *(float2*)&g1out[n * 128 + c0] = o;
}

// layer2: 64 threads/node, 1 col each; fused bias+ReLU+BN2+(@Wl+bl); 4 nodes/block.

__global__ __launch_bounds__(256) void gather64_k(const int* __restrict__ cursor, const unsigned short* __restrict__ esrc,
                                                  const ushort16* __restrict__ hsb, const float* __restrict__ dinv,
                                                  const float* __restrict__ b2,
                                                  const float* __restrict__ g2, const float* __restrict__ be2,
                                                  const float* __restrict__ m2, const float* __restrict__ v2,
                                                  const float* __restrict__ Wl, const float* __restrict__ bl,
                                                  float* __restrict__ out) {
    int tid = threadIdx.x;
    int n = blockIdx.x * 4 + (tid >> 6);
    int lane = tid & 63;
    int beg = (n == 0) ? 0 : cursor[n - 1];
    int end = cursor[n];
    float acc = 0.f;
    int e = beg;
    for (; e + 1 < end; e += 2) {
        int s0 = esrc[e], s1 = esrc[e + 1];
        float a = __uint_as_float(((uint32)hsb[s0 * 64 + lane]) << 16);
        float b = __uint_as_float(((uint32)hsb[s1 * 64 + lane]) << 16);
        acc += a; acc += b;
    }
    if (e < end) acc += __uint_as_float(((uint32)hsb[(int)esrc[e] * 64 + lane]) << 16);
    float self = __uint_as_float(((uint32)hsb[n * 64 + lane]) << 16);
    float di = dinv[n];
    float val = di * (acc + self) + b2[lane];
    val = fmaxf(val, 0.f);
    float gg = (val - m2[lane]) * rsqrtf(v2[lane] + BN_EPS) * g2[lane] + be2[lane];
    float p0 = gg * Wl[lane * 2];
    float p1 = gg * Wl[lane * 2 + 1];
#pragma unroll
    for (int d = 32; d > 0; d >>= 1) {
        p0 += __shfl_down(p0, d);
        p1 += __shfl_down(p1, d);
    }
    if (lane == 0) {
        out[n * 2] = p0 + bl[0];
        out[n * 2 + 1] = p1 + bl[1];
    }
}

// ================= launch =================

extern "C" void kernel_launch(void* const* d_in, const int* in_sizes, int n_in,
                              void* d_out, int out_size, void* d_ws, size_t ws_size,
                              hipStream_t stream) {
    const float* x   = (const float*)d_in[0];
    const int*   ei  = (const int*)d_in[1];
    const float* W1  = (const float*)d_in[2];
    const float* b1  = (const float*)d_in[3];
    const float* W2  = (const float*)d_in[4];
    const float* b2  = (const float*)d_in[5];
    const float* g1p = (const float*)d_in[6];
    const float* be1 = (const float*)d_in[7];
    const float* m1  = (const float*)d_in[8];
    const float* v1  = (const float*)d_in[9];
    const float* g2p = (const float*)d_in[10];
    const float* be2 = (const float*)d_in[11];
    const float* m2  = (const float*)d_in[12];
    const float* v2  = (const float*)d_in[13];
    const float* Wl  = (const float*)d_in[14];
    const float* bl  = (const float*)d_in[15];
    float* out = (float*)d_out;

    // workspace layout in 4B units
    float* ws = (float*)d_ws;
    float*          dinv    = ws;                                   // [0, 50000)
    int*            cursor  = (int*)(ws + 50000);                   // [50000, 100000)
    int*            gcnt    = (int*)(ws + 100000);                  // [100000, 100391)
    int*            gbase   = (int*)(ws + 100391);                  // [100391, 100783)
    int*            gcursor = (int*)(ws + 100783);                  // [100783, 101174)
    uint32*         ebin    = (uint32*)(ws + 101184);               // 1.6M u32
    unsigned short* esrc    = (unsigned short*)(ws + 1701184);      // 1.6M u16
    ushort16*       hs1b    = (ushort16*)(ws + 2501184);            // 6.4M bf16
    float*          g1buf   = ws + 5701184;                         // 6.4M f32
    ushort16*       hs2b    = (ushort16*)(ws + 12101184);           // 3.2M bf16

    hipMemsetAsync(gcnt, 0, NB * sizeof(int), stream);
    bcount_k<<<NEB, 256, 0, stream>>>(ei, gcnt);
    bscan_k<<<1, 512, 0, stream>>>(gcnt, gbase, gcursor);
    bin_k<<<NEB, 256, 0, stream>>>(ei, gcursor, ebin);
    bsort_k<<<NB, 256, 0, stream>>>(gbase, ebin, esrc, cursor, dinv);

    gemm1_k<<<(N_NODES + 63) / 64, 256, 0, stream>>>(x, W1, dinv, hs1b);
    gather128_k<<<(N_NODES + 3) / 4, 256, 0, stream>>>(cursor, esrc, hs1b, dinv, b1, g1p, be1, m1, v1, g1buf);
    gemm2_k<<<(N_NODES + 63) / 64, 256, 0, stream>>>(g1buf, W2, dinv, hs2b);
    gather64_k<<<(N_NODES + 3) / 4, 256, 0, stream>>>(cursor, esrc, hs2b, dinv, b2, g2p, be2, m2, v2, Wl, bl, out);
}

// Round 9
// 352.982 us; speedup vs baseline: 12.3185x; 1.1937x over previous
//
#include <hip/hip_runtime.h>

#define N_NODES 50000
#define N_EDGES 1600000
#define BN_EPS 1e-5f

#define BSH 7
#define BKN 128                                   // nodes per bucket
#define NB  ((N_NODES + BKN - 1) / BKN)           // 391 buckets
#define EPT 16
#define EPB (256 * EPT)                           // 4096 edges per block
#define NEB ((N_EDGES + EPB - 1) / EPB)           // 391 blocks

typedef unsigned int uint32;
typedef unsigned short ushort16;

__device__ __forceinline__ float bf_lo(uint32 u) { return __uint_as_float(u << 16); }
__device__ __forceinline__ float bf_hi(uint32 u) { return __uint_as_float(u & 0xFFFF0000u); }
__device__ __forceinline__ ushort16 f2bf(float f) {
    uint32 u = __float_as_uint(f);
    u = (u + 0x7FFFu + ((u >> 16) & 1u)) >> 16;     // RNE
    return (ushort16)u;
}

// ================= CSR build (bucketed, low write-amplification) =================

__global__ __launch_bounds__(256) void bcount_k(const int* __restrict__ ei, int* __restrict__ gcnt) {
    __shared__ int h[NB];
    int t = threadIdx.x;
    for (int i = t; i < NB; i += 256) h[i] = 0;
    __syncthreads();
    int eb = blockIdx.x * EPB;
#pragma unroll
    for (int i = 0; i < EPT; ++i) {
        int e = eb + i * 256 + t;
        if (e < N_EDGES) atomicAdd(&h[ei[N_EDGES + e] >> BSH], 1);
    }
    __syncthreads();
    for (int i = t; i < NB; i += 256) if (h[i]) atomicAdd(&gcnt[i], h[i]);
}

__global__ __launch_bounds__(512) void bscan_k(const int* __restrict__ gcnt, int* __restrict__ gbase,
                                               int* __restrict__ gcursor) {
    __shared__ int wsum[8];
    int t = threadIdx.x;
    int v = (t < NB) ? gcnt[t] : 0;
    int s = v;
#pragma unroll
    for (int d = 1; d < 64; d <<= 1) {
        int n = __shfl_up(s, d);
        if ((t & 63) >= d) s += n;
    }
    if ((t & 63) == 63) wsum[t >> 6] = s;
    __syncthreads();
    if (t < 8) {
        int w = wsum[t];
#pragma unroll
        for (int d = 1; d < 8; d <<= 1) {
            int n = __shfl_up(w, d);
            if (t >= d) w += n;
        }
        wsum[t] = w;
    }
    __syncthreads();
    int wb = (t >> 6) ? wsum[(t >> 6) - 1] : 0;
    int excl = wb + s - v;
    if (t < NB) { gbase[t] = excl; gcursor[t] = excl; }
    if (t == NB - 1) gbase[NB] = excl + v;
}

__global__ __launch_bounds__(256) void bin_k(const int* __restrict__ ei, int* __restrict__ gcursor,
                                             uint32* __restrict__ ebin) {
    __shared__ int hcnt[NB];
    __shared__ int hbase[NB];
    int t = threadIdx.x;
    for (int i = t; i < NB; i += 256) hcnt[i] = 0;
    __syncthreads();
    int sv[EPT], dv[EPT];
    int eb = blockIdx.x * EPB;
#pragma unroll
    for (int i = 0; i < EPT; ++i) {
        int e = eb + i * 256 + t;
        if (e < N_EDGES) {
            sv[i] = ei[e];
            dv[i] = ei[N_EDGES + e];
            atomicAdd(&hcnt[dv[i] >> BSH], 1);
        } else {
            dv[i] = -1;
        }
    }
    __syncthreads();
    for (int i = t; i < NB; i += 256) {
        int c = hcnt[i];
        hbase[i] = c ? atomicAdd(&gcursor[i], c) : 0;
    }
    __syncthreads();
    for (int i = t; i < NB; i += 256) hcnt[i] = 0;
    __syncthreads();
#pragma unroll
    for (int i = 0; i < EPT; ++i) {
        if (dv[i] >= 0) {
            int b = dv[i] >> BSH;
            int off = atomicAdd(&hcnt[b], 1);
            ebin[hbase[b] + off] = (uint32)sv[i] | ((uint32)(dv[i] & (BKN - 1)) << 16);
        }
    }
}

__global__ __launch_bounds__(256) void bsort_k(const int* __restrict__ gbase, const uint32* __restrict__ ebin,
                                               unsigned short* __restrict__ esrc, int* __restrict__ cursor,
                                               float* __restrict__ dinv) {
    __shared__ int hcnt[BKN];
    __shared__ int hoff[BKN];
    __shared__ int wsum2[2];
    int b = blockIdx.x;
    int t = threadIdx.x;
    int ebeg = gbase[b], eend = gbase[b + 1];
    int n0 = b << BSH;
    int nn = min(BKN, N_NODES - n0);
    if (t < BKN) hcnt[t] = 0;
    __syncthreads();
    for (int e = ebeg + t; e < eend; e += 256) atomicAdd(&hcnt[ebin[e] >> 16], 1);
    __syncthreads();
    int v = (t < BKN) ? hcnt[t] : 0;
    int s = v;
#pragma unroll
    for (int d = 1; d < 64; d <<= 1) {
        int x = __shfl_up(s, d);
        if ((t & 63) >= d) s += x;
    }
    if (t < BKN && (t & 63) == 63) wsum2[t >> 6] = s;
    __syncthreads();
    int wb = ((t >> 6) == 1) ? wsum2[0] : 0;
    int incl = wb + s;
    if (t < nn) {
        cursor[n0 + t] = ebeg + incl;
        dinv[n0 + t] = rsqrtf((float)v + 1.0f);
        hoff[t] = ebeg + incl - v;
    }
    __syncthreads();
    for (int e = ebeg + t; e < eend; e += 256) {
        uint32 p = ebin[e];
        int ld = p >> 16;
        int pos = atomicAdd(&hoff[ld], 1);
        esrc[pos] = (unsigned short)(p & 0xFFFFu);
    }
}

// ================= GEMM1: hs1 = bf16( (x @ W1) * dinv[row] )  [50000,256]x[256,128] =================

__global__ __launch_bounds__(256) void gemm1_k(const float* __restrict__ X, const float* __restrict__ W,
                                               const float* __restrict__ dinv, ushort16* __restrict__ outb) {
    __shared__ float xs[64][64 + 4];
    __shared__ float ws[64][128];
    int tid = threadIdx.x;
    int row0 = blockIdx.x * 64;
    int tx = tid & 15, ty = tid >> 4;
    float acc[4][8] = {};
    for (int k0 = 0; k0 < 256; k0 += 64) {
#pragma unroll
        for (int i = 0; i < 4; ++i) {
            int f = tid + i * 256;
            int r = f >> 4;
            int kk = (f & 15) << 2;
            int grow = row0 + r;
            float4 v = make_float4(0.f, 0.f, 0.f, 0.f);
            if (grow < N_NODES) v = *(const float4*)&X[grow * 256 + k0 + kk];
            xs[kk + 0][r] = v.x; xs[kk + 1][r] = v.y; xs[kk + 2][r] = v.z; xs[kk + 3][r] = v.w;
        }
#pragma unroll
        for (int i = 0; i < 8; ++i) {
            int f = tid + i * 256;
            int r = f >> 5;
            int c = (f & 31) << 2;
            *(float4*)&ws[r][c] = *(const float4*)&W[(k0 + r) * 128 + c];
        }
        __syncthreads();
#pragma unroll 8
        for (int k = 0; k < 64; ++k) {
            float4 xv = *(const float4*)&xs[k][ty * 4];
            float wv[8];
            *(float4*)&wv[0] = *(const float4*)&ws[k][tx * 8];
            *(float4*)&wv[4] = *(const float4*)&ws[k][tx * 8 + 4];
#pragma unroll
            for (int c = 0; c < 8; ++c) {
                acc[0][c] += xv.x * wv[c];
                acc[1][c] += xv.y * wv[c];
                acc[2][c] += xv.z * wv[c];
                acc[3][c] += xv.w * wv[c];
            }
        }
        __syncthreads();
    }
#pragma unroll
    for (int r = 0; r < 4; ++r) {
        int grow = row0 + ty * 4 + r;
        if (grow < N_NODES) {
            float s = dinv[grow];
            uint32 w[4];
#pragma unroll
            for (int c = 0; c < 4; ++c) {
                uint32 lo = (uint32)f2bf(acc[r][2 * c] * s);
                uint32 hi = (uint32)f2bf(acc[r][2 * c + 1] * s);
                w[c] = lo | (hi << 16);
            }
            uint4 o; o.x = w[0]; o.y = w[1]; o.z = w[2]; o.w = w[3];
            *(uint4*)&outb[grow * 128 + tx * 8] = o;
        }
    }
}

// ================= GEMM2: hs2 = bf16( (g1 @ W2) * dinv[row] )  [50000,128]x[128,64] =================

__global__ __launch_bounds__(256) void gemm2_k(const float* __restrict__ X, const float* __restrict__ W,
                                               const float* __restrict__ dinv, ushort16* __restrict__ outb) {
    __shared__ float xs[64][64 + 4];
    __shared__ float ws[64][64];
    int tid = threadIdx.x;
    int row0 = blockIdx.x * 64;
    int tx = tid & 15, ty = tid >> 4;
    float acc[4][4] = {};
    for (int k0 = 0; k0 < 128; k0 += 64) {
#pragma unroll
        for (int i = 0; i < 4; ++i) {
            int f = tid + i * 256;
            int r = f >> 4;
            int kk = (f & 15) << 2;
            int grow = row0 + r;
            float4 v = make_float4(0.f, 0.f, 0.f, 0.f);
            if (grow < N_NODES) v = *(const float4*)&X[grow * 128 + k0 + kk];
            xs[kk + 0][r] = v.x; xs[kk + 1][r] = v.y; xs[kk + 2][r] = v.z; xs[kk + 3][r] = v.w;
        }
#pragma unroll
        for (int i = 0; i < 4; ++i) {
            int f = tid + i * 256;
            int r = f >> 4;
            int c = (f & 15) << 2;
            *(float4*)&ws[r][c] = *(const float4*)&W[(k0 + r) * 64 + c];
        }
        __syncthreads();
#pragma unroll 8
        for (int k = 0; k < 64; ++k) {
            float4 xv = *(const float4*)&xs[k][ty * 4];
            float4 wv = *(const float4*)&ws[k][tx * 4];
#pragma unroll
            for (int c = 0; c < 4; ++c) {
                float w = (c == 0) ? wv.x : (c == 1) ? wv.y : (c == 2) ? wv.z : wv.w;
                acc[0][c] += xv.x * w;
                acc[1][c] += xv.y * w;
                acc[2][c] += xv.z * w;
                acc[3][c] += xv.w * w;
            }
        }
        __syncthreads();
    }
#pragma unroll
    for (int r = 0; r < 4; ++r) {
        int grow = row0 + ty * 4 + r;
        if (grow < N_NODES) {
            float s = dinv[grow];
            ushort4 o;
            o.x = f2bf(acc[r][0] * s); o.y = f2bf(acc[r][1] * s);
            o.z = f2bf(acc[r][2] * s); o.w = f2bf(acc[r][3] * s);
            *(ushort4*)&outb[grow * 64 + tx * 4] = o;
        }
    }
}

// ================= gathers (bf16 payload, ushort esrc, 8-deep MLP) =================
// layer1: 64 threads/node, thread owns cols {2l, 2l+1}; 4 nodes/block.

__global__ __launch_bounds__(256) void gather128_k(const int* __restrict__ cursor, const unsigned short* __restrict__ esrc,
                                                   const ushort16* __restrict__ hsb, const float* __restrict__ dinv,
                                                   const float* __restrict__ bias,
                                                   const float* __restrict__ gamma, const float* __restrict__ beta,
                                                   const float* __restrict__ mean, const float* __restrict__ var,
                                                   float* __restrict__ g1out) {
    int tid = threadIdx.x;
    int n = blockIdx.x * 4 + (tid >> 6);
    int lane = tid & 63;
    int c0 = lane * 2;
    int beg = (n == 0) ? 0 : cursor[n - 1];
    int end = cursor[n];
    float acc0 = 0.f, acc1 = 0.f;
    int e = beg;
    for (; e + 7 < end; e += 8) {
        int s0 = esrc[e + 0], s1 = esrc[e + 1], s2 = esrc[e + 2], s3 = esrc[e + 3];
        int s4 = esrc[e + 4], s5 = esrc[e + 5], s6 = esrc[e + 6], s7 = esrc[e + 7];
        uint32 u0 = *(const uint32*)&hsb[s0 * 128 + c0];
        uint32 u1 = *(const uint32*)&hsb[s1 * 128 + c0];
        uint32 u2 = *(const uint32*)&hsb[s2 * 128 + c0];
        uint32 u3 = *(const uint32*)&hsb[s3 * 128 + c0];
        uint32 u4 = *(const uint32*)&hsb[s4 * 128 + c0];
        uint32 u5 = *(const uint32*)&hsb[s5 * 128 + c0];
        uint32 u6 = *(const uint32*)&hsb[s6 * 128 + c0];
        uint32 u7 = *(const uint32*)&hsb[s7 * 128 + c0];
        acc0 += bf_lo(u0); acc1 += bf_hi(u0);
        acc0 += bf_lo(u1); acc1 += bf_hi(u1);
        acc0 += bf_lo(u2); acc1 += bf_hi(u2);
        acc0 += bf_lo(u3); acc1 += bf_hi(u3);
        acc0 += bf_lo(u4); acc1 += bf_hi(u4);
        acc0 += bf_lo(u5); acc1 += bf_hi(u5);
        acc0 += bf_lo(u6); acc1 += bf_hi(u6);
        acc0 += bf_lo(u7); acc1 += bf_hi(u7);
    }
    for (; e < end; ++e) {
        uint32 u = *(const uint32*)&hsb[(int)esrc[e] * 128 + c0];
        acc0 += bf_lo(u); acc1 += bf_hi(u);
    }
    uint32 us = *(const uint32*)&hsb[n * 128 + c0];
    float di = dinv[n];
    float v0 = di * (acc0 + bf_lo(us)) + bias[c0];
    float v1 = di * (acc1 + bf_hi(us)) + bias[c0 + 1];
    v0 = fmaxf(v0, 0.f);
    v1 = fmaxf(v1, 0.f);
    float g0 = (v0 - mean[c0]) * rsqrtf(var[c0] + BN_EPS) * gamma[c0] + beta[c0];
    float g1 = (v1 - mean[c0 + 1]) * rsqrtf(var[c0 + 1] + BN_EPS) * gamma[c0 + 1] + beta[c0 + 1];
    float2 o; o.x = g0; o.y = g1;
    *(float2*)&g1out[n * 128 + c0] = o;
}

// layer2: 64 threads/node, 1 col each; fused bias+ReLU+BN2+(@Wl+bl); 4 nodes/block.

__global__ __launch_bounds__(256) void gather64_k(const int* __restrict__ cursor, const unsigned short* __restrict__ esrc,
                                                  const ushort16* __restrict__ hsb, const float* __restrict__ dinv,
                                                  const float* __restrict__ b2,
                                                  const float* __restrict__ g2, const float* __restrict__ be2,
                                                  const float* __restrict__ m2, const float* __restrict__ v2,
                                                  const float* __restrict__ Wl, const float* __restrict__ bl,
                                                  float* __restrict__ out) {
    int tid = threadIdx.x;
    int n = blockIdx.x * 4 + (tid >> 6);
    int lane = tid & 63;
    int beg = (n == 0) ? 0 : cursor[n - 1];
    int end = cursor[n];
    float acc = 0.f;
    int e = beg;
    for (; e + 7 < end; e += 8) {
        int s0 = esrc[e + 0], s1 = esrc[e + 1], s2 = esrc[e + 2], s3 = esrc[e + 3];
        int s4 = esrc[e + 4], s5 = esrc[e + 5], s6 = esrc[e + 6], s7 = esrc[e + 7];
        float a0 = __uint_as_float(((uint32)hsb[s0 * 64 + lane]) << 16);
        float a1 = __uint_as_float(((uint32)hsb[s1 * 64 + lane]) << 16);
        float a2 = __uint_as_float(((uint32)hsb[s2 * 64 + lane]) << 16);
        float a3 = __uint_as_float(((uint32)hsb[s3 * 64 + lane]) << 16);
        float a4 = __uint_as_float(((uint32)hsb[s4 * 64 + lane]) << 16);
        float a5 = __uint_as_float(((uint32)hsb[s5 * 64 + lane]) << 16);
        float a6 = __uint_as_float(((uint32)hsb[s6 * 64 + lane]) << 16);
        float a7 = __uint_as_float(((uint32)hsb[s7 * 64 + lane]) << 16);
        acc += a0; acc += a1; acc += a2; acc += a3;
        acc += a4; acc += a5; acc += a6; acc += a7;
    }
    for (; e < end; ++e) acc += __uint_as_float(((uint32)hsb[(int)esrc[e] * 64 + lane]) << 16);
    float self = __uint_as_float(((uint32)hsb[n * 64 + lane]) << 16);
    float di = dinv[n];
    float val = di * (acc + self) + b2[lane];
    val = fmaxf(val, 0.f);
    float gg = (val - m2[lane]) * rsqrtf(v2[lane] + BN_EPS) * g2[lane] + be2[lane];
    float p0 = gg * Wl[lane * 2];
    float p1 = gg * Wl[lane * 2 + 1];
#pragma unroll
    for (int d = 32; d > 0; d >>= 1) {
        p0 += __shfl_down(p0, d);
        p1 += __shfl_down(p1, d);
    }
    if (lane == 0) {
        out[n * 2] = p0 + bl[0];
        out[n * 2 + 1] = p1 + bl[1];
    }
}

// ================= launch =================

extern "C" void kernel_launch(void* const* d_in, const int* in_sizes, int n_in,
                              void* d_out, int out_size, void* d_ws, size_t ws_size,
                              hipStream_t stream) {
    const float* x   = (const float*)d_in[0];
    const int*   ei  = (const int*)d_in[1];
    const float* W1  = (const float*)d_in[2];
    const float* b1  = (const float*)d_in[3];
    const float* W2  = (const float*)d_in[4];
    const float* b2  = (const float*)d_in[5];
    const float* g1p = (const float*)d_in[6];
    const float* be1 = (const float*)d_in[7];
    const float* m1  = (const float*)d_in[8];
    const float* v1  = (const float*)d_in[9];
    const float* g2p = (const float*)d_in[10];
    const float* be2 = (const float*)d_in[11];
    const float* m2  = (const float*)d_in[12];
    const float* v2  = (const float*)d_in[13];
    const float* Wl  = (const float*)d_in[14];
    const float* bl  = (const float*)d_in[15];
    float* out = (float*)d_out;

    // workspace layout in 4B units
    float* ws = (float*)d_ws;
    float*          dinv    = ws;                                   // [0, 50000)
    int*            cursor  = (int*)(ws + 50000);                   // [50000, 100000)
    int*            gcnt    = (int*)(ws + 100000);                  // [100000, 100391)
    int*            gbase   = (int*)(ws + 100391);                  // [100391, 100783)
    int*            gcursor = (int*)(ws + 100783);                  // [100783, 101174)
    uint32*         ebin    = (uint32*)(ws + 101184);               // 1.6M u32
    unsigned short* esrc    = (unsigned short*)(ws + 1701184);      // 1.6M u16
    ushort16*       hs1b    = (ushort16*)(ws + 2501184);            // 6.4M bf16
    float*          g1buf   = ws + 5701184;                         // 6.4M f32
    ushort16*       hs2b    = (ushort16*)(ws + 12101184);           // 3.2M bf16

    hipMemsetAsync(gcnt, 0, NB * sizeof(int), stream);
    bcount_k<<<NEB, 256, 0, stream>>>(ei, gcnt);
    bscan_k<<<1, 512, 0, stream>>>(gcnt, gbase, gcursor);
    bin_k<<<NEB, 256, 0, stream>>>(ei, gcursor, ebin);
    bsort_k<<<NB, 256, 0, stream>>>(gbase, ebin, esrc, cursor, dinv);

    gemm1_k<<<(N_NODES + 63) / 64, 256, 0, stream>>>(x, W1, dinv, hs1b);
    gather128_k<<<(N_NODES + 3) / 4, 256, 0, stream>>>(cursor, esrc, hs1b, dinv, b1, g1p, be1, m1, v1, g1buf);
    gemm2_k<<<(N_NODES + 63) / 64, 256, 0, stream>>>(g1buf, W2, dinv, hs2b);
    gather64_k<<<(N_NODES + 3) / 4, 256, 0, stream>>>(cursor, esrc, hs2b, dinv, b2, g2p, be2, m2, v2, Wl, bl, out);
}

// Round 10
// 344.833 us; speedup vs baseline: 12.6096x; 1.0236x over previous
//
#include <hip/hip_runtime.h>

#define N_NODES 50000
#define N_EDGES 1600000
#define BN_EPS 1e-5f

#define BSH 7
#define BKN 128                                   // nodes per bucket
#define NB  ((N_NODES + BKN - 1) / BKN)           // 391 buckets
#define EPT 16
#define EPB (256 * EPT)                           // 4096 edges per block
#define NEB ((N_EDGES + EPB - 1) / EPB)           // 391 blocks

typedef unsigned int uint32;
typedef unsigned short ushort16;

__device__ __forceinline__ float bf_lo(uint32 u) { return __uint_as_float(u << 16); }
__device__ __forceinline__ float bf_hi(uint32 u) { return __uint_as_float(u & 0xFFFF0000u); }
__device__ __forceinline__ ushort16 f2bf(float f) {
    uint32 u = __float_as_uint(f);
    u = (u + 0x7FFFu + ((u >> 16) & 1u)) >> 16;     // RNE
    return (ushort16)u;
}

// ================= CSR build (bucketed, low write-amplification) =================

__global__ __launch_bounds__(256) void bcount_k(const int* __restrict__ ei, int* __restrict__ gcnt) {
    __shared__ int h[NB];
    int t = threadIdx.x;
    for (int i = t; i < NB; i += 256) h[i] = 0;
    __syncthreads();
    int eb = blockIdx.x * EPB;
#pragma unroll
    for (int i = 0; i < EPT; ++i) {
        int e = eb + i * 256 + t;
        if (e < N_EDGES) atomicAdd(&h[ei[N_EDGES + e] >> BSH], 1);
    }
    __syncthreads();
    for (int i = t; i < NB; i += 256) if (h[i]) atomicAdd(&gcnt[i], h[i]);
}

__global__ __launch_bounds__(512) void bscan_k(const int* __restrict__ gcnt, int* __restrict__ gbase,
                                               int* __restrict__ gcursor) {
    __shared__ int wsum[8];
    int t = threadIdx.x;
    int v = (t < NB) ? gcnt[t] : 0;
    int s = v;
#pragma unroll
    for (int d = 1; d < 64; d <<= 1) {
        int n = __shfl_up(s, d);
        if ((t & 63) >= d) s += n;
    }
    if ((t & 63) == 63) wsum[t >> 6] = s;
    __syncthreads();
    if (t < 8) {
        int w = wsum[t];
#pragma unroll
        for (int d = 1; d < 8; d <<= 1) {
            int n = __shfl_up(w, d);
            if (t >= d) w += n;
        }
        wsum[t] = w;
    }
    __syncthreads();
    int wb = (t >> 6) ? wsum[(t >> 6) - 1] : 0;
    int excl = wb + s - v;
    if (t < NB) { gbase[t] = excl; gcursor[t] = excl; }
    if (t == NB - 1) gbase[NB] = excl + v;
}

__global__ __launch_bounds__(256) void bin_k(const int* __restrict__ ei, int* __restrict__ gcursor,
                                             uint32* __restrict__ ebin) {
    __shared__ int hcnt[NB];
    __shared__ int hbase[NB];
    int t = threadIdx.x;
    for (int i = t; i < NB; i += 256) hcnt[i] = 0;
    __syncthreads();
    int sv[EPT], dv[EPT];
    int eb = blockIdx.x * EPB;
#pragma unroll
    for (int i = 0; i < EPT; ++i) {
        int e = eb + i * 256 + t;
        if (e < N_EDGES) {
            sv[i] = ei[e];
            dv[i] = ei[N_EDGES + e];
            atomicAdd(&hcnt[dv[i] >> BSH], 1);
        } else {
            dv[i] = -1;
        }
    }
    __syncthreads();
    for (int i = t; i < NB; i += 256) {
        int c = hcnt[i];
        hbase[i] = c ? atomicAdd(&gcursor[i], c) : 0;
    }
    __syncthreads();
    for (int i = t; i < NB; i += 256) hcnt[i] = 0;
    __syncthreads();
#pragma unroll
    for (int i = 0; i < EPT; ++i) {
        if (dv[i] >= 0) {
            int b = dv[i] >> BSH;
            int off = atomicAdd(&hcnt[b], 1);
            ebin[hbase[b] + off] = (uint32)sv[i] | ((uint32)(dv[i] & (BKN - 1)) << 16);
        }
    }
}

__global__ __launch_bounds__(256) void bsort_k(const int* __restrict__ gbase, const uint32* __restrict__ ebin,
                                               unsigned short* __restrict__ esrc, int* __restrict__ cursor,
                                               float* __restrict__ dinv) {
    __shared__ int hcnt[BKN];
    __shared__ int hoff[BKN];
    __shared__ int wsum2[2];
    int b = blockIdx.x;
    int t = threadIdx.x;
    int ebeg = gbase[b], eend = gbase[b + 1];
    int n0 = b << BSH;
    int nn = min(BKN, N_NODES - n0);
    if (t < BKN) hcnt[t] = 0;
    __syncthreads();
    for (int e = ebeg + t; e < eend; e += 256) atomicAdd(&hcnt[ebin[e] >> 16], 1);
    __syncthreads();
    int v = (t < BKN) ? hcnt[t] : 0;
    int s = v;
#pragma unroll
    for (int d = 1; d < 64; d <<= 1) {
        int x = __shfl_up(s, d);
        if ((t & 63) >= d) s += x;
    }
    if (t < BKN && (t & 63) == 63) wsum2[t >> 6] = s;
    __syncthreads();
    int wb = ((t >> 6) == 1) ? wsum2[0] : 0;
    int incl = wb + s;
    if (t < nn) {
        cursor[n0 + t] = ebeg + incl;
        dinv[n0 + t] = rsqrtf((float)v + 1.0f);
        hoff[t] = ebeg + incl - v;
    }
    __syncthreads();
    for (int e = ebeg + t; e < eend; e += 256) {
        uint32 p = ebin[e];
        int ld = p >> 16;
        int pos = atomicAdd(&hoff[ld], 1);
        esrc[pos] = (unsigned short)(p & 0xFFFFu);
    }
}

// ================= GEMM1: hs1 = bf16( (x @ W1) * dinv[row] )  [50000,256]x[256,128] =================
// BM=64, BN=128, BK=32. LDS conflict-free: xs XOR-granule-swizzled, ws even/odd de-interleaved.

__global__ __launch_bounds__(256) void gemm1_k(const float* __restrict__ X, const float* __restrict__ W,
                                               const float* __restrict__ dinv, ushort16* __restrict__ outb) {
    __shared__ float xs[32 * 64];    // [krow][Xrow], phys granule = (Xrow>>2) ^ (krow>>2)   (8 KB)
    __shared__ float ws[32 * 128];   // [krow][col], phys f4 = (g&1)*16 + (g>>1)             (16 KB)
    int tid = threadIdx.x;
    int row0 = blockIdx.x * 64;
    int tx = tid & 15, ty = tid >> 4;
    float acc[4][8] = {};
    for (int k0 = 0; k0 < 256; k0 += 32) {
        // stage X tile: 64 rows x 32 k = 512 float4, transposed store (swizzled, 2-way free)
#pragma unroll
        for (int i = 0; i < 2; ++i) {
            int f = tid + i * 256;
            int r = f >> 3;                 // X row in tile 0..63
            int kg = f & 7;                 // k-granule 0..7
            int grow = row0 + r;
            float4 v = make_float4(0.f, 0.f, 0.f, 0.f);
            if (grow < N_NODES) v = *(const float4*)&X[grow * 256 + k0 + kg * 4];
            int gc = r >> 2, el = r & 3;
            int pg = gc ^ kg;               // krow>>2 == kg for all 4 j
            xs[(kg * 4 + 0) * 64 + pg * 4 + el] = v.x;
            xs[(kg * 4 + 1) * 64 + pg * 4 + el] = v.y;
            xs[(kg * 4 + 2) * 64 + pg * 4 + el] = v.z;
            xs[(kg * 4 + 3) * 64 + pg * 4 + el] = v.w;
        }
        // stage W tile: 32 k x 128 = 1024 float4, de-interleaved
#pragma unroll
        for (int i = 0; i < 4; ++i) {
            int f = tid + i * 256;
            int r = f >> 5;                 // k row 0..31
            int g = f & 31;                 // logical granule
            int p = (g & 1) * 16 + (g >> 1);
            *(float4*)&ws[r * 128 + p * 4] = *(const float4*)&W[(k0 + r) * 128 + g * 4];
        }
        __syncthreads();
#pragma unroll 8
        for (int k = 0; k < 32; ++k) {
            float4 xv = *(const float4*)&xs[k * 64 + ((ty ^ (k >> 2)) << 2)];
            float wv[8];
            *(float4*)&wv[0] = *(const float4*)&ws[k * 128 + tx * 4];        // cols tx*8..+3
            *(float4*)&wv[4] = *(const float4*)&ws[k * 128 + 64 + tx * 4];   // cols tx*8+4..+7
#pragma unroll
            for (int c = 0; c < 8; ++c) {
                acc[0][c] += xv.x * wv[c];
                acc[1][c] += xv.y * wv[c];
                acc[2][c] += xv.z * wv[c];
                acc[3][c] += xv.w * wv[c];
            }
        }
        __syncthreads();
    }
#pragma unroll
    for (int r = 0; r < 4; ++r) {
        int grow = row0 + ty * 4 + r;
        if (grow < N_NODES) {
            float s = dinv[grow];
            uint32 w[4];
#pragma unroll
            for (int c = 0; c < 4; ++c) {
                uint32 lo = (uint32)f2bf(acc[r][2 * c] * s);
                uint32 hi = (uint32)f2bf(acc[r][2 * c + 1] * s);
                w[c] = lo | (hi << 16);
            }
            uint4 o; o.x = w[0]; o.y = w[1]; o.z = w[2]; o.w = w[3];
            *(uint4*)&outb[grow * 128 + tx * 8] = o;
        }
    }
}

// ================= GEMM2: hs2 = bf16( (g1 @ W2) * dinv[row] )  [50000,128]x[128,64] =================
// BM=64, BN=64, BK=32. xs swizzled as gemm1; ws reads already structural-min.

__global__ __launch_bounds__(256) void gemm2_k(const float* __restrict__ X, const float* __restrict__ W,
                                               const float* __restrict__ dinv, ushort16* __restrict__ outb) {
    __shared__ float xs[32 * 64];    // 8 KB, swizzled
    __shared__ float ws[32 * 64];    // 8 KB, plain
    int tid = threadIdx.x;
    int row0 = blockIdx.x * 64;
    int tx = tid & 15, ty = tid >> 4;
    float acc[4][4] = {};
    for (int k0 = 0; k0 < 128; k0 += 32) {
#pragma unroll
        for (int i = 0; i < 2; ++i) {
            int f = tid + i * 256;
            int r = f >> 3;
            int kg = f & 7;
            int grow = row0 + r;
            float4 v = make_float4(0.f, 0.f, 0.f, 0.f);
            if (grow < N_NODES) v = *(const float4*)&X[grow * 128 + k0 + kg * 4];
            int gc = r >> 2, el = r & 3;
            int pg = gc ^ kg;
            xs[(kg * 4 + 0) * 64 + pg * 4 + el] = v.x;
            xs[(kg * 4 + 1) * 64 + pg * 4 + el] = v.y;
            xs[(kg * 4 + 2) * 64 + pg * 4 + el] = v.z;
            xs[(kg * 4 + 3) * 64 + pg * 4 + el] = v.w;
        }
        // stage W: 32 k x 64 = 512 float4
#pragma unroll
        for (int i = 0; i < 2; ++i) {
            int f = tid + i * 256;
            int r = f >> 4;
            int g = f & 15;
            *(float4*)&ws[r * 64 + g * 4] = *(const float4*)&W[(k0 + r) * 64 + g * 4];
        }
        __syncthreads();
#pragma unroll 8
        for (int k = 0; k < 32; ++k) {
            float4 xv = *(const float4*)&xs[k * 64 + ((ty ^ (k >> 2)) << 2)];
            float4 wv = *(const float4*)&ws[k * 64 + tx * 4];
#pragma unroll
            for (int c = 0; c < 4; ++c) {
                float w = (c == 0) ? wv.x : (c == 1) ? wv.y : (c == 2) ? wv.z : wv.w;
                acc[0][c] += xv.x * w;
                acc[1][c] += xv.y * w;
                acc[2][c] += xv.z * w;
                acc[3][c] += xv.w * w;
            }
        }
        __syncthreads();
    }
#pragma unroll
    for (int r = 0; r < 4; ++r) {
        int grow = row0 + ty * 4 + r;
        if (grow < N_NODES) {
            float s = dinv[grow];
            ushort4 o;
            o.x = f2bf(acc[r][0] * s); o.y = f2bf(acc[r][1] * s);
            o.z = f2bf(acc[r][2] * s); o.w = f2bf(acc[r][3] * s);
            *(ushort4*)&outb[grow * 64 + tx * 4] = o;
        }
    }
}

// ================= gathers (bf16 payload, ushort esrc, 8-deep MLP) =================

__global__ __launch_bounds__(256) void gather128_k(const int* __restrict__ cursor, const unsigned short* __restrict__ esrc,
                                                   const ushort16* __restrict__ hsb, const float* __restrict__ dinv,
                                                   const float* __restrict__ bias,
                                                   const float* __restrict__ gamma, const float* __restrict__ beta,
                                                   const float* __restrict__ mean, const float* __restrict__ var,
                                                   float* __restrict__ g1out) {
    int tid = threadIdx.x;
    int n = blockIdx.x * 4 + (tid >> 6);
    int lane = tid & 63;
    int c0 = lane * 2;
    int beg = (n == 0) ? 0 : cursor[n - 1];
    int end = cursor[n];
    float acc0 = 0.f, acc1 = 0.f;
    int e = beg;
    for (; e + 7 < end; e += 8) {
        int s0 = esrc[e + 0], s1 = esrc[e + 1], s2 = esrc[e + 2], s3 = esrc[e + 3];
        int s4 = esrc[e + 4], s5 = esrc[e + 5], s6 = esrc[e + 6], s7 = esrc[e + 7];
        uint32 u0 = *(const uint32*)&hsb[s0 * 128 + c0];
        uint32 u1 = *(const uint32*)&hsb[s1 * 128 + c0];
        uint32 u2 = *(const uint32*)&hsb[s2 * 128 + c0];
        uint32 u3 = *(const uint32*)&hsb[s3 * 128 + c0];
        uint32 u4 = *(const uint32*)&hsb[s4 * 128 + c0];
        uint32 u5 = *(const uint32*)&hsb[s5 * 128 + c0];
        uint32 u6 = *(const uint32*)&hsb[s6 * 128 + c0];
        uint32 u7 = *(const uint32*)&hsb[s7 * 128 + c0];
        acc0 += bf_lo(u0); acc1 += bf_hi(u0);
        acc0 += bf_lo(u1); acc1 += bf_hi(u1);
        acc0 += bf_lo(u2); acc1 += bf_hi(u2);
        acc0 += bf_lo(u3); acc1 += bf_hi(u3);
        acc0 += bf_lo(u4); acc1 += bf_hi(u4);
        acc0 += bf_lo(u5); acc1 += bf_hi(u5);
        acc0 += bf_lo(u6); acc1 += bf_hi(u6);
        acc0 += bf_lo(u7); acc1 += bf_hi(u7);
    }
    for (; e < end; ++e) {
        uint32 u = *(const uint32*)&hsb[(int)esrc[e] * 128 + c0];
        acc0 += bf_lo(u); acc1 += bf_hi(u);
    }
    uint32 us = *(const uint32*)&hsb[n * 128 + c0];
    float di = dinv[n];
    float v0 = di * (acc0 + bf_lo(us)) + bias[c0];
    float v1 = di * (acc1 + bf_hi(us)) + bias[c0 + 1];
    v0 = fmaxf(v0, 0.f);
    v1 = fmaxf(v1, 0.f);
    float g0 = (v0 - mean[c0]) * rsqrtf(var[c0] + BN_EPS) * gamma[c0] + beta[c0];
    float g1 = (v1 - mean[c0 + 1]) * rsqrtf(var[c0 + 1] + BN_EPS) * gamma[c0 + 1] + beta[c0 + 1];
    float2 o; o.x = g0; o.y = g1;
    *(float2*)&g1out[n * 128 + c0] = o;
}

__global__ __launch_bounds__(256) void gather64_k(const int* __restrict__ cursor, const unsigned short* __restrict__ esrc,
                                                  const ushort16* __restrict__ hsb, const float* __restrict__ dinv,
                                                  const float* __restrict__ b2,
                                                  const float* __restrict__ g2, const float* __restrict__ be2,
                                                  const float* __restrict__ m2, const float* __restrict__ v2,
                                                  const float* __restrict__ Wl, const float* __restrict__ bl,
                                                  float* __restrict__ out) {
    int tid = threadIdx.x;
    int n = blockIdx.x * 4 + (tid >> 6);
    int lane = tid & 63;
    int beg = (n == 0) ? 0 : cursor[n - 1];
    int end = cursor[n];
    float acc = 0.f;
    int e = beg;
    for (; e + 7 < end; e += 8) {
        int s0 = esrc[e + 0], s1 = esrc[e + 1], s2 = esrc[e + 2], s3 = esrc[e + 3];
        int s4 = esrc[e + 4], s5 = esrc[e + 5], s6 = esrc[e + 6], s7 = esrc[e + 7];
        float a0 = __uint_as_float(((uint32)hsb[s0 * 64 + lane]) << 16);
        float a1 = __uint_as_float(((uint32)hsb[s1 * 64 + lane]) << 16);
        float a2 = __uint_as_float(((uint32)hsb[s2 * 64 + lane]) << 16);
        float a3 = __uint_as_float(((uint32)hsb[s3 * 64 + lane]) << 16);
        float a4 = __uint_as_float(((uint32)hsb[s4 * 64 + lane]) << 16);
        float a5 = __uint_as_float(((uint32)hsb[s5 * 64 + lane]) << 16);
        float a6 = __uint_as_float(((uint32)hsb[s6 * 64 + lane]) << 16);
        float a7 = __uint_as_float(((uint32)hsb[s7 * 64 + lane]) << 16);
        acc += a0; acc += a1; acc += a2; acc += a3;
        acc += a4; acc += a5; acc += a6; acc += a7;
    }
    for (; e < end; ++e) acc += __uint_as_float(((uint32)hsb[(int)esrc[e] * 64 + lane]) << 16);
    float self = __uint_as_float(((uint32)hsb[n * 64 + lane]) << 16);
    float di = dinv[n];
    float val = di * (acc + self) + b2[lane];
    val = fmaxf(val, 0.f);
    float gg = (val - m2[lane]) * rsqrtf(v2[lane] + BN_EPS) * g2[lane] + be2[lane];
    float p0 = gg * Wl[lane * 2];
    float p1 = gg * Wl[lane * 2 + 1];
#pragma unroll
    for (int d = 32; d > 0; d >>= 1) {
        p0 += __shfl_down(p0, d);
        p1 += __shfl_down(p1, d);
    }
    if (lane == 0) {
        out[n * 2] = p0 + bl[0];
        out[n * 2 + 1] = p1 + bl[1];
    }
}

// ================= launch =================

extern "C" void kernel_launch(void* const* d_in, const int* in_sizes, int n_in,
                              void* d_out, int out_size, void* d_ws, size_t ws_size,
                              hipStream_t stream) {
    const float* x   = (const float*)d_in[0];
    const int*   ei  = (const int*)d_in[1];
    const float* W1  = (const float*)d_in[2];
    const float* b1  = (const float*)d_in[3];
    const float* W2  = (const float*)d_in[4];
    const float* b2  = (const float*)d_in[5];
    const float* g1p = (const float*)d_in[6];
    const float* be1 = (const float*)d_in[7];
    const float* m1  = (const float*)d_in[8];
    const float* v1  = (const float*)d_in[9];
    const float* g2p = (const float*)d_in[10];
    const float* be2 = (const float*)d_in[11];
    const float* m2  = (const float*)d_in[12];
    const float* v2  = (const float*)d_in[13];
    const float* Wl  = (const float*)d_in[14];
    const float* bl  = (const float*)d_in[15];
    float* out = (float*)d_out;

    // workspace layout in 4B units
    float* ws = (float*)d_ws;
    float*          dinv    = ws;                                   // [0, 50000)
    int*            cursor  = (int*)(ws + 50000);                   // [50000, 100000)
    int*            gcnt    = (int*)(ws + 100000);                  // [100000, 100391)
    int*            gbase   = (int*)(ws + 100391);                  // [100391, 100783)
    int*            gcursor = (int*)(ws + 100783);                  // [100783, 101174)
    uint32*         ebin    = (uint32*)(ws + 101184);               // 1.6M u32
    unsigned short* esrc    = (unsigned short*)(ws + 1701184);      // 1.6M u16
    ushort16*       hs1b    = (ushort16*)(ws + 2501184);            // 6.4M bf16
    float*          g1buf   = ws + 5701184;                         // 6.4M f32
    ushort16*       hs2b    = (ushort16*)(ws + 12101184);           // 3.2M bf16

    hipMemsetAsync(gcnt, 0, NB * sizeof(int), stream);
    bcount_k<<<NEB, 256, 0, stream>>>(ei, gcnt);
    bscan_k<<<1, 512, 0, stream>>>(gcnt, gbase, gcursor);
    bin_k<<<NEB, 256, 0, stream>>>(ei, gcursor, ebin);
    bsort_k<<<NB, 256, 0, stream>>>(gbase, ebin, esrc, cursor, dinv);

    gemm1_k<<<(N_NODES + 63) / 64, 256, 0, stream>>>(x, W1, dinv, hs1b);
    gather128_k<<<(N_NODES + 3) / 4, 256, 0, stream>>>(cursor, esrc, hs1b, dinv, b1, g1p, be1, m1, v1, g1buf);
    gemm2_k<<<(N_NODES + 63) / 64, 256, 0, stream>>>(g1buf, W2, dinv, hs2b);
    gather64_k<<<(N_NODES + 3) / 4, 256, 0, stream>>>(cursor, esrc, hs2b, dinv, b2, g2p, be2, m2, v2, Wl, bl, out);
}

// Round 11
// 313.919 us; speedup vs baseline: 13.8514x; 1.0985x over previous
//
#include <hip/hip_runtime.h>

#define N_NODES 50000
#define N_EDGES 1600000
#define BN_EPS 1e-5f

#define BSH 7
#define BKN 128
#define NB  ((N_NODES + BKN - 1) / BKN)           // 391
#define EPT 16
#define EPB (256 * EPT)
#define NEB ((N_EDGES + EPB - 1) / EPB)           // 391

typedef unsigned int uint32;
typedef unsigned short ushort16;
typedef __attribute__((ext_vector_type(8))) short short8v;   // 8 bf16 = 4 VGPR
typedef __attribute__((ext_vector_type(4))) float f32x4;

__device__ __forceinline__ float bf_lo(uint32 u) { return __uint_as_float(u << 16); }
__device__ __forceinline__ float bf_hi(uint32 u) { return __uint_as_float(u & 0xFFFF0000u); }
__device__ __forceinline__ ushort16 f2bf(float f) {
    uint32 u = __float_as_uint(f);
    u = (u + 0x7FFFu + ((u >> 16) & 1u)) >> 16;     // RNE
    return (ushort16)u;
}

// ================= CSR build (bucketed) =================

__global__ __launch_bounds__(256) void bcount_k(const int* __restrict__ ei, int* __restrict__ gcnt) {
    __shared__ int h[NB];
    int t = threadIdx.x;
    for (int i = t; i < NB; i += 256) h[i] = 0;
    __syncthreads();
    int eb = blockIdx.x * EPB;
#pragma unroll
    for (int i = 0; i < EPT; ++i) {
        int e = eb + i * 256 + t;
        if (e < N_EDGES) atomicAdd(&h[ei[N_EDGES + e] >> BSH], 1);
    }
    __syncthreads();
    for (int i = t; i < NB; i += 256) if (h[i]) atomicAdd(&gcnt[i], h[i]);
}

__global__ __launch_bounds__(512) void bscan_k(const int* __restrict__ gcnt, int* __restrict__ gbase,
                                               int* __restrict__ gcursor) {
    __shared__ int wsum[8];
    int t = threadIdx.x;
    int v = (t < NB) ? gcnt[t] : 0;
    int s = v;
#pragma unroll
    for (int d = 1; d < 64; d <<= 1) {
        int n = __shfl_up(s, d);
        if ((t & 63) >= d) s += n;
    }
    if ((t & 63) == 63) wsum[t >> 6] = s;
    __syncthreads();
    if (t < 8) {
        int w = wsum[t];
#pragma unroll
        for (int d = 1; d < 8; d <<= 1) {
            int n = __shfl_up(w, d);
            if (t >= d) w += n;
        }
        wsum[t] = w;
    }
    __syncthreads();
    int wb = (t >> 6) ? wsum[(t >> 6) - 1] : 0;
    int excl = wb + s - v;
    if (t < NB) { gbase[t] = excl; gcursor[t] = excl; }
    if (t == NB - 1) gbase[NB] = excl + v;
}

__global__ __launch_bounds__(256) void bin_k(const int* __restrict__ ei, int* __restrict__ gcursor,
                                             uint32* __restrict__ ebin) {
    __shared__ int hcnt[NB];
    __shared__ int hbase[NB];
    int t = threadIdx.x;
    for (int i = t; i < NB; i += 256) hcnt[i] = 0;
    __syncthreads();
    int sv[EPT], dv[EPT];
    int eb = blockIdx.x * EPB;
#pragma unroll
    for (int i = 0; i < EPT; ++i) {
        int e = eb + i * 256 + t;
        if (e < N_EDGES) {
            sv[i] = ei[e];
            dv[i] = ei[N_EDGES + e];
            atomicAdd(&hcnt[dv[i] >> BSH], 1);
        } else {
            dv[i] = -1;
        }
    }
    __syncthreads();
    for (int i = t; i < NB; i += 256) {
        int c = hcnt[i];
        hbase[i] = c ? atomicAdd(&gcursor[i], c) : 0;
    }
    __syncthreads();
    for (int i = t; i < NB; i += 256) hcnt[i] = 0;
    __syncthreads();
#pragma unroll
    for (int i = 0; i < EPT; ++i) {
        if (dv[i] >= 0) {
            int b = dv[i] >> BSH;
            int off = atomicAdd(&hcnt[b], 1);
            ebin[hbase[b] + off] = (uint32)sv[i] | ((uint32)(dv[i] & (BKN - 1)) << 16);
        }
    }
}

__global__ __launch_bounds__(256) void bsort_k(const int* __restrict__ gbase, const uint32* __restrict__ ebin,
                                               unsigned short* __restrict__ esrc, int* __restrict__ cursor,
                                               float* __restrict__ dinv) {
    __shared__ int hcnt[BKN];
    __shared__ int hoff[BKN];
    __shared__ int wsum2[2];
    int b = blockIdx.x;
    int t = threadIdx.x;
    int ebeg = gbase[b], eend = gbase[b + 1];
    int n0 = b << BSH;
    int nn = min(BKN, N_NODES - n0);
    if (t < BKN) hcnt[t] = 0;
    __syncthreads();
    for (int e = ebeg + t; e < eend; e += 256) atomicAdd(&hcnt[ebin[e] >> 16], 1);
    __syncthreads();
    int v = (t < BKN) ? hcnt[t] : 0;
    int s = v;
#pragma unroll
    for (int d = 1; d < 64; d <<= 1) {
        int x = __shfl_up(s, d);
        if ((t & 63) >= d) s += x;
    }
    if (t < BKN && (t & 63) == 63) wsum2[t >> 6] = s;
    __syncthreads();
    int wb = ((t >> 6) == 1) ? wsum2[0] : 0;
    int incl = wb + s;
    if (t < nn) {
        cursor[n0 + t] = ebeg + incl;
        dinv[n0 + t] = rsqrtf((float)v + 1.0f);
        hoff[t] = ebeg + incl - v;
    }
    __syncthreads();
    for (int e = ebeg + t; e < eend; e += 256) {
        uint32 p = ebin[e];
        int ld = p >> 16;
        int pos = atomicAdd(&hoff[ld], 1);
        esrc[pos] = (unsigned short)(p & 0xFFFFu);
    }
}

// ================= W1^T bf16 prepass: WT[c][k] = bf16(W1[k][c])  [128][256] =================

__global__ __launch_bounds__(256) void w1t_k(const float* __restrict__ W, ushort16* __restrict__ WT) {
    int id = blockIdx.x * 256 + threadIdx.x;
    if (id >= 128 * 256) return;
    int c = id >> 8, k = id & 255;
    WT[c * 256 + k] = f2bf(W[k * 128 + c]);
}

// ================= GEMM1 (MFMA bf16): hs1 = bf16( (x @ W1) * dinv[row] ) =================
// Block: 128 rows x 64 cols, 256 thr = 4 waves, wave = 32 rows x 64 cols = 2x4 MFMA 16x16x32 tiles.
// LDS frag-packed: slot = tile*64 + lane, 16B per lane (k = (l>>4)*4 + (j&3) + 16*(j>>2)).

__global__ __launch_bounds__(256) void gemm1_k(const float* __restrict__ X, const ushort16* __restrict__ WT,
                                               const float* __restrict__ dinv, ushort16* __restrict__ outb) {
    __shared__ uint4 la[512];   // 8 row-tiles x 64 lanes  (8 KB)
    __shared__ uint4 lb[256];   // 4 col-tiles x 64 lanes  (4 KB)
    int tid = threadIdx.x;
    int w = tid >> 6, l = tid & 63;
    int row0 = (blockIdx.x >> 1) * 128;
    int col0 = (blockIdx.x & 1) * 64;
    f32x4 acc[2][4] = {};
    for (int k0 = 0; k0 < 256; k0 += 32) {
        // stage A: 2 slots/thread
#pragma unroll
        for (int i = 0; i < 2; ++i) {
            int s = tid + i * 256;
            int rt = s >> 6, sl = s & 63;
            int r = row0 + rt * 16 + (sl & 15);
            int g = sl >> 4;
            float4 x0 = make_float4(0.f, 0.f, 0.f, 0.f), x1 = x0;
            if (r < N_NODES) {
                x0 = *(const float4*)&X[r * 256 + k0 + 4 * g];
                x1 = *(const float4*)&X[r * 256 + k0 + 16 + 4 * g];
            }
            uint4 v;
            v.x = (uint32)f2bf(x0.x) | ((uint32)f2bf(x0.y) << 16);
            v.y = (uint32)f2bf(x0.z) | ((uint32)f2bf(x0.w) << 16);
            v.z = (uint32)f2bf(x1.x) | ((uint32)f2bf(x1.y) << 16);
            v.w = (uint32)f2bf(x1.z) | ((uint32)f2bf(x1.w) << 16);
            la[s] = v;
        }
        // stage B: 1 slot/thread
        {
            int ct = tid >> 6, sl = tid & 63;
            int n = col0 + ct * 16 + (sl & 15);
            int g = sl >> 4;
            uint2 lo = *(const uint2*)&WT[n * 256 + k0 + 4 * g];
            uint2 hi = *(const uint2*)&WT[n * 256 + k0 + 16 + 4 * g];
            uint4 v; v.x = lo.x; v.y = lo.y; v.z = hi.x; v.w = hi.y;
            lb[tid] = v;
        }
        __syncthreads();
        short8v a0 = *(short8v*)&la[(w * 2 + 0) * 64 + l];
        short8v a1 = *(short8v*)&la[(w * 2 + 1) * 64 + l];
#pragma unroll
        for (int ct = 0; ct < 4; ++ct) {
            short8v b = *(short8v*)&lb[ct * 64 + l];
            acc[0][ct] = __builtin_amdgcn_mfma_f32_16x16x32_bf16(a0, b, acc[0][ct], 0, 0, 0);
            acc[1][ct] = __builtin_amdgcn_mfma_f32_16x16x32_bf16(a1, b, acc[1][ct], 0, 0, 0);
        }
        __syncthreads();
    }
    // epilogue: D row = rt*16 + (l>>4)*4 + q, col = col0 + ct*16 + (l&15)
#pragma unroll
    for (int i = 0; i < 2; ++i) {
#pragma unroll
        for (int q = 0; q < 4; ++q) {
            int row = row0 + (w * 2 + i) * 16 + (l >> 4) * 4 + q;
            if (row < N_NODES) {
                float s = dinv[row];
#pragma unroll
                for (int ct = 0; ct < 4; ++ct) {
                    int col = col0 + ct * 16 + (l & 15);
                    outb[row * 128 + col] = f2bf(acc[i][ct][q] * s);
                }
            }
        }
    }
}

// ================= GEMM2 (fp32): hs2 = bf16( (g1 @ W2) * dinv[row] )  [50000,128]x[128,64] =================

__global__ __launch_bounds__(256) void gemm2_k(const float* __restrict__ X, const float* __restrict__ W,
                                               const float* __restrict__ dinv, ushort16* __restrict__ outb) {
    __shared__ float xs[32 * 64];
    __shared__ float ws[32 * 64];
    int tid = threadIdx.x;
    int row0 = blockIdx.x * 64;
    int tx = tid & 15, ty = tid >> 4;
    float acc[4][4] = {};
    for (int k0 = 0; k0 < 128; k0 += 32) {
#pragma unroll
        for (int i = 0; i < 2; ++i) {
            int f = tid + i * 256;
            int r = f >> 3;
            int kg = f & 7;
            int grow = row0 + r;
            float4 v = make_float4(0.f, 0.f, 0.f, 0.f);
            if (grow < N_NODES) v = *(const float4*)&X[grow * 128 + k0 + kg * 4];
            int gc = r >> 2, el = r & 3;
            int pg = gc ^ kg;
            xs[(kg * 4 + 0) * 64 + pg * 4 + el] = v.x;
            xs[(kg * 4 + 1) * 64 + pg * 4 + el] = v.y;
            xs[(kg * 4 + 2) * 64 + pg * 4 + el] = v.z;
            xs[(kg * 4 + 3) * 64 + pg * 4 + el] = v.w;
        }
#pragma unroll
        for (int i = 0; i < 2; ++i) {
            int f = tid + i * 256;
            int r = f >> 4;
            int g = f & 15;
            *(float4*)&ws[r * 64 + g * 4] = *(const float4*)&W[(k0 + r) * 64 + g * 4];
        }
        __syncthreads();
#pragma unroll 8
        for (int k = 0; k < 32; ++k) {
            float4 xv = *(const float4*)&xs[k * 64 + ((ty ^ (k >> 2)) << 2)];
            float4 wv = *(const float4*)&ws[k * 64 + tx * 4];
#pragma unroll
            for (int c = 0; c < 4; ++c) {
                float w = (c == 0) ? wv.x : (c == 1) ? wv.y : (c == 2) ? wv.z : wv.w;
                acc[0][c] += xv.x * w;
                acc[1][c] += xv.y * w;
                acc[2][c] += xv.z * w;
                acc[3][c] += xv.w * w;
            }
        }
        __syncthreads();
    }
#pragma unroll
    for (int r = 0; r < 4; ++r) {
        int grow = row0 + ty * 4 + r;
        if (grow < N_NODES) {
            float s = dinv[grow];
            ushort4 o;
            o.x = f2bf(acc[r][0] * s); o.y = f2bf(acc[r][1] * s);
            o.z = f2bf(acc[r][2] * s); o.w = f2bf(acc[r][3] * s);
            *(ushort4*)&outb[grow * 64 + tx * 4] = o;
        }
    }
}

// ================= gathers (bf16 payload, ushort esrc, 8-deep MLP) =================

__global__ __launch_bounds__(256) void gather128_k(const int* __restrict__ cursor, const unsigned short* __restrict__ esrc,
                                                   const ushort16* __restrict__ hsb, const float* __restrict__ dinv,
                                                   const float* __restrict__ bias,
                                                   const float* __restrict__ gamma, const float* __restrict__ beta,
                                                   const float* __restrict__ mean, const float* __restrict__ var,
                                                   float* __restrict__ g1out) {
    int tid = threadIdx.x;
    int n = blockIdx.x * 4 + (tid >> 6);
    int lane = tid & 63;
    int c0 = lane * 2;
    int beg = (n == 0) ? 0 : cursor[n - 1];
    int end = cursor[n];
    float acc0 = 0.f, acc1 = 0.f;
    int e = beg;
    for (; e + 7 < end; e += 8) {
        int s0 = esrc[e + 0], s1 = esrc[e + 1], s2 = esrc[e + 2], s3 = esrc[e + 3];
        int s4 = esrc[e + 4], s5 = esrc[e + 5], s6 = esrc[e + 6], s7 = esrc[e + 7];
        uint32 u0 = *(const uint32*)&hsb[s0 * 128 + c0];
        uint32 u1 = *(const uint32*)&hsb[s1 * 128 + c0];
        uint32 u2 = *(const uint32*)&hsb[s2 * 128 + c0];
        uint32 u3 = *(const uint32*)&hsb[s3 * 128 + c0];
        uint32 u4 = *(const uint32*)&hsb[s4 * 128 + c0];
        uint32 u5 = *(const uint32*)&hsb[s5 * 128 + c0];
        uint32 u6 = *(const uint32*)&hsb[s6 * 128 + c0];
        uint32 u7 = *(const uint32*)&hsb[s7 * 128 + c0];
        acc0 += bf_lo(u0); acc1 += bf_hi(u0);
        acc0 += bf_lo(u1); acc1 += bf_hi(u1);
        acc0 += bf_lo(u2); acc1 += bf_hi(u2);
        acc0 += bf_lo(u3); acc1 += bf_hi(u3);
        acc0 += bf_lo(u4); acc1 += bf_hi(u4);
        acc0 += bf_lo(u5); acc1 += bf_hi(u5);
        acc0 += bf_lo(u6); acc1 += bf_hi(u6);
        acc0 += bf_lo(u7); acc1 += bf_hi(u7);
    }
    for (; e < end; ++e) {
        uint32 u = *(const uint32*)&hsb[(int)esrc[e] * 128 + c0];
        acc0 += bf_lo(u); acc1 += bf_hi(u);
    }
    uint32 us = *(const uint32*)&hsb[n * 128 + c0];
    float di = dinv[n];
    float v0 = di * (acc0 + bf_lo(us)) + bias[c0];
    float v1 = di * (acc1 + bf_hi(us)) + bias[c0 + 1];
    v0 = fmaxf(v0, 0.f);
    v1 = fmaxf(v1, 0.f);
    float g0 = (v0 - mean[c0]) * rsqrtf(var[c0] + BN_EPS) * gamma[c0] + beta[c0];
    float g1 = (v1 - mean[c0 + 1]) * rsqrtf(var[c0 + 1] + BN_EPS) * gamma[c0 + 1] + beta[c0 + 1];
    float2 o; o.x = g0; o.y = g1;
    *(float2*)&g1out[n * 128 + c0] = o;
}

__global__ __launch_bounds__(256) void gather64_k(const int* __restrict__ cursor, const unsigned short* __restrict__ esrc,
                                                  const ushort16* __restrict__ hsb, const float* __restrict__ dinv,
                                                  const float* __restrict__ b2,
                                                  const float* __restrict__ g2, const float* __restrict__ be2,
                                                  const float* __restrict__ m2, const float* __restrict__ v2,
                                                  const float* __restrict__ Wl, const float* __restrict__ bl,
                                                  float* __restrict__ out) {
    int tid = threadIdx.x;
    int n = blockIdx.x * 4 + (tid >> 6);
    int lane = tid & 63;
    int beg = (n == 0) ? 0 : cursor[n - 1];
    int end = cursor[n];
    float acc = 0.f;
    int e = beg;
    for (; e + 7 < end; e += 8) {
        int s0 = esrc[e + 0], s1 = esrc[e + 1], s2 = esrc[e + 2], s3 = esrc[e + 3];
        int s4 = esrc[e + 4], s5 = esrc[e + 5], s6 = esrc[e + 6], s7 = esrc[e + 7];
        float a0 = __uint_as_float(((uint32)hsb[s0 * 64 + lane]) << 16);
        float a1 = __uint_as_float(((uint32)hsb[s1 * 64 + lane]) << 16);
        float a2 = __uint_as_float(((uint32)hsb[s2 * 64 + lane]) << 16);
        float a3 = __uint_as_float(((uint32)hsb[s3 * 64 + lane]) << 16);
        float a4 = __uint_as_float(((uint32)hsb[s4 * 64 + lane]) << 16);
        float a5 = __uint_as_float(((uint32)hsb[s5 * 64 + lane]) << 16);
        float a6 = __uint_as_float(((uint32)hsb[s6 * 64 + lane]) << 16);
        float a7 = __uint_as_float(((uint32)hsb[s7 * 64 + lane]) << 16);
        acc += a0; acc += a1; acc += a2; acc += a3;
        acc += a4; acc += a5; acc += a6; acc += a7;
    }
    for (; e < end; ++e) acc += __uint_as_float(((uint32)hsb[(int)esrc[e] * 64 + lane]) << 16);
    float self = __uint_as_float(((uint32)hsb[n * 64 + lane]) << 16);
    float di = dinv[n];
    float val = di * (acc + self) + b2[lane];
    val = fmaxf(val, 0.f);
    float gg = (val - m2[lane]) * rsqrtf(v2[lane] + BN_EPS) * g2[lane] + be2[lane];
    float p0 = gg * Wl[lane * 2];
    float p1 = gg * Wl[lane * 2 + 1];
#pragma unroll
    for (int d = 32; d > 0; d >>= 1) {
        p0 += __shfl_down(p0, d);
        p1 += __shfl_down(p1, d);
    }
    if (lane == 0) {
        out[n * 2] = p0 + bl[0];
        out[n * 2 + 1] = p1 + bl[1];
    }
}

// ================= launch =================

extern "C" void kernel_launch(void* const* d_in, const int* in_sizes, int n_in,
                              void* d_out, int out_size, void* d_ws, size_t ws_size,
                              hipStream_t stream) {
    const float* x   = (const float*)d_in[0];
    const int*   ei  = (const int*)d_in[1];
    const float* W1  = (const float*)d_in[2];
    const float* b1  = (const float*)d_in[3];
    const float* W2  = (const float*)d_in[4];
    const float* b2  = (const float*)d_in[5];
    const float* g1p = (const float*)d_in[6];
    const float* be1 = (const float*)d_in[7];
    const float* m1  = (const float*)d_in[8];
    const float* v1  = (const float*)d_in[9];
    const float* g2p = (const float*)d_in[10];
    const float* be2 = (const float*)d_in[11];
    const float* m2  = (const float*)d_in[12];
    const float* v2  = (const float*)d_in[13];
    const float* Wl  = (const float*)d_in[14];
    const float* bl  = (const float*)d_in[15];
    float* out = (float*)d_out;

    // workspace layout in 4B units
    float* ws = (float*)d_ws;
    float*          dinv    = ws;                                   // [0, 50000)
    int*            cursor  = (int*)(ws + 50000);                   // [50000, 100000)
    int*            gcnt    = (int*)(ws + 100000);
    int*            gbase   = (int*)(ws + 100391);
    int*            gcursor = (int*)(ws + 100783);
    uint32*         ebin    = (uint32*)(ws + 101184);               // 1.6M u32
    unsigned short* esrc    = (unsigned short*)(ws + 1701184);      // 1.6M u16
    ushort16*       hs1b    = (ushort16*)(ws + 2501184);            // 6.4M bf16
    float*          g1buf   = ws + 5701184;                         // 6.4M f32
    ushort16*       hs2b    = (ushort16*)(ws + 12101184);           // 3.2M bf16
    ushort16*       w1t     = (ushort16*)(ws + 13701184);           // 32768 bf16 (W1^T)

    hipMemsetAsync(gcnt, 0, NB * sizeof(int), stream);
    bcount_k<<<NEB, 256, 0, stream>>>(ei, gcnt);
    bscan_k<<<1, 512, 0, stream>>>(gcnt, gbase, gcursor);
    bin_k<<<NEB, 256, 0, stream>>>(ei, gcursor, ebin);
    w1t_k<<<128, 256, 0, stream>>>(W1, w1t);
    bsort_k<<<NB, 256, 0, stream>>>(gbase, ebin, esrc, cursor, dinv);

    gemm1_k<<<782, 256, 0, stream>>>(x, w1t, dinv, hs1b);
    gather128_k<<<(N_NODES + 3) / 4, 256, 0, stream>>>(cursor, esrc, hs1b, dinv, b1, g1p, be1, m1, v1, g1buf);
    gemm2_k<<<(N_NODES + 63) / 64, 256, 0, stream>>>(g1buf, W2, dinv, hs2b);
    gather64_k<<<(N_NODES + 3) / 4, 256, 0, stream>>>(cursor, esrc, hs2b, dinv, b2, g2p, be2, m2, v2, Wl, bl, out);
}